// Round 9
// baseline (355.174 us; speedup 1.0000x reference)
//
#include <hip/hip_runtime.h>
#include <stdint.h>

#define T 2048
#define D 512
#define NH 8
#define DH 64
#define L 2

typedef float floatx4 __attribute__((ext_vector_type(4)));
typedef short shortx8 __attribute__((ext_vector_type(8)));
typedef unsigned short u16;
typedef unsigned short u16x4 __attribute__((ext_vector_type(4)));

__device__ __forceinline__ u16 f2bf(float f) {
    union { float f; uint32_t u; } c; c.f = f;
    uint32_t u = c.u;
    u += 0x7fffu + ((u >> 16) & 1u);
    return (u16)(u >> 16);
}

__device__ __forceinline__ float bf2f(u16 v) {
    union { uint32_t u; float f; } c; c.u = ((uint32_t)v) << 16;
    return c.f;
}

__device__ __forceinline__ void load_lds16(const void* g, void* l) {
    __builtin_amdgcn_global_load_lds((const __attribute__((address_space(1))) void*)g,
                                     (__attribute__((address_space(3))) void*)l,
                                     16, 0, 0);
}

// ---------------- pre: weight transposes (z<24) + add_pos (z==24) ----------
struct TransJobs {
    const float* src[6];
    u16* dst[6];
    const float* x;
    const float* pos;
    float* h;
};

__global__ __launch_bounds__(256) void pre_kernel(TransJobs j) {
    __shared__ float tile[32][33];
    int tid = threadIdx.x;
    if (blockIdx.z == 24) {
        int idx = (blockIdx.y * 32 + blockIdx.x) * 256 + tid;
        float4 xv = ((const float4*)j.x)[idx];
        float4 pv = ((const float4*)j.pos)[idx];
        float4 r;
        r.x = xv.x + pv.x; r.y = xv.y + pv.y; r.z = xv.z + pv.z; r.w = xv.w + pv.w;
        ((float4*)j.h)[idx] = r;
        ((float4*)j.h)[idx + (T * D / 4)] = r;
        return;
    }
    int m = blockIdx.z >> 2, slice = blockIdx.z & 3;
    int R = (m == 5) ? 1024 : 512;
    int C = (m == 4) ? 1024 : 512;
    if (blockIdx.x * 32 >= C || blockIdx.y * 32 >= R) return;
    const float* in = j.src[m] + (size_t)slice * R * C;
    u16* out = j.dst[m] + (size_t)slice * R * C;
    int tx = tid & 31, ty = tid >> 5;
    int x = blockIdx.x * 32 + tx;
    int y0 = blockIdx.y * 32;
#pragma unroll
    for (int i = 0; i < 4; i++)
        tile[ty + i * 8][tx] = in[(size_t)(y0 + ty + i * 8) * C + x];
    __syncthreads();
    int ox = y0 + tx;
#pragma unroll
    for (int i = 0; i < 4; i++)
        out[(size_t)(blockIdx.x * 32 + ty + i * 8) * R + ox] = f2bf(tile[tx][ty + i * 8]);
}

// ---------------- LayerNorm + optional 4x bf16-partial fold ----------------
__global__ __launch_bounds__(256) void ln_res_kernel(float* __restrict__ h,
                                                     const u16* __restrict__ part,
                                                     const float* __restrict__ w0,
                                                     const float* __restrict__ b0,
                                                     u16* __restrict__ out, int l) {
    int row = blockIdx.x * 4 + (threadIdx.x >> 6);
    int lane = threadIdx.x & 63;
    int s = row >> 11;
    int c0 = lane * 4;
    float* xr = h + (size_t)row * D;
    float4 v0 = *(const float4*)(xr + c0);
    float4 v1 = *(const float4*)(xr + c0 + 256);
    if (part) {
        const u16* pr = part + (size_t)s * 4 * T * D + (size_t)(row & (T - 1)) * D;
#pragma unroll
        for (int kc = 0; kc < 4; kc++) {
            u16x4 a0 = *(const u16x4*)(pr + c0), a1 = *(const u16x4*)(pr + c0 + 256);
            v0.x += bf2f(a0[0]); v0.y += bf2f(a0[1]); v0.z += bf2f(a0[2]); v0.w += bf2f(a0[3]);
            v1.x += bf2f(a1[0]); v1.y += bf2f(a1[1]); v1.z += bf2f(a1[2]); v1.w += bf2f(a1[3]);
            pr += (size_t)T * D;
        }
        *(float4*)(xr + c0) = v0;
        *(float4*)(xr + c0 + 256) = v1;
    }
    float sum = v0.x + v0.y + v0.z + v0.w + v1.x + v1.y + v1.z + v1.w;
    float sq = v0.x*v0.x + v0.y*v0.y + v0.z*v0.z + v0.w*v0.w
             + v1.x*v1.x + v1.y*v1.y + v1.z*v1.z + v1.w*v1.w;
#pragma unroll
    for (int d2 = 1; d2 < 64; d2 <<= 1) { sum += __shfl_xor(sum, d2); sq += __shfl_xor(sq, d2); }
    float mu = sum * (1.0f / D);
    float var = sq * (1.0f / D) - mu * mu;
    float rstd = rsqrtf(var + 1e-5f);
    const float* w = w0 + (size_t)(s * L + l) * D;
    const float* b = b0 + (size_t)(s * L + l) * D;
    u16x4 p0, p1;
#pragma unroll
    for (int jj = 0; jj < 4; jj++) {
        float a = (jj == 0 ? v0.x : jj == 1 ? v0.y : jj == 2 ? v0.z : v0.w);
        p0[jj] = f2bf((a - mu) * rstd * w[c0 + jj] + b[c0 + jj]);
        float c = (jj == 0 ? v1.x : jj == 1 ? v1.y : jj == 2 ? v1.z : v1.w);
        p1[jj] = f2bf((c - mu) * rstd * w[c0 + 256 + jj] + b[c0 + 256 + jj]);
    }
    *(u16x4*)(out + (size_t)row * D + c0) = p0;
    *(u16x4*)(out + (size_t)row * D + c0 + 256) = p1;
}

// ---------------- Final LayerNorm (+ 4x bf16 partial fold) -> fp32 out -----
__global__ __launch_bounds__(256) void lnf_kernel(const float* __restrict__ h,
                                                  const u16* __restrict__ part,
                                                  const float* __restrict__ w,
                                                  const float* __restrict__ b,
                                                  float* __restrict__ out) {
    int row = blockIdx.x * 4 + (threadIdx.x >> 6);
    int lane = threadIdx.x & 63;
    int s = row >> 11;
    int c0 = lane * 4;
    const float* xr = h + (size_t)row * D;
    float4 v0 = *(const float4*)(xr + c0);
    float4 v1 = *(const float4*)(xr + c0 + 256);
    const u16* pr = part + (size_t)s * 4 * T * D + (size_t)(row & (T - 1)) * D;
#pragma unroll
    for (int kc = 0; kc < 4; kc++) {
        u16x4 a0 = *(const u16x4*)(pr + c0), a1 = *(const u16x4*)(pr + c0 + 256);
        v0.x += bf2f(a0[0]); v0.y += bf2f(a0[1]); v0.z += bf2f(a0[2]); v0.w += bf2f(a0[3]);
        v1.x += bf2f(a1[0]); v1.y += bf2f(a1[1]); v1.z += bf2f(a1[2]); v1.w += bf2f(a1[3]);
        pr += (size_t)T * D;
    }
    float sum = v0.x + v0.y + v0.z + v0.w + v1.x + v1.y + v1.z + v1.w;
    float sq = v0.x*v0.x + v0.y*v0.y + v0.z*v0.z + v0.w*v0.w
             + v1.x*v1.x + v1.y*v1.y + v1.z*v1.z + v1.w*v1.w;
#pragma unroll
    for (int d2 = 1; d2 < 64; d2 <<= 1) { sum += __shfl_xor(sum, d2); sq += __shfl_xor(sq, d2); }
    float mu = sum * (1.0f / D);
    float var = sq * (1.0f / D) - mu * mu;
    float rstd = rsqrtf(var + 1e-5f);
    float4 r0, r1;
    r0.x = (v0.x - mu) * rstd * w[c0+0] + b[c0+0];
    r0.y = (v0.y - mu) * rstd * w[c0+1] + b[c0+1];
    r0.z = (v0.z - mu) * rstd * w[c0+2] + b[c0+2];
    r0.w = (v0.w - mu) * rstd * w[c0+3] + b[c0+3];
    r1.x = (v1.x - mu) * rstd * w[c0+256+0] + b[c0+256+0];
    r1.y = (v1.y - mu) * rstd * w[c0+256+1] + b[c0+256+1];
    r1.z = (v1.z - mu) * rstd * w[c0+256+2] + b[c0+256+2];
    r1.w = (v1.w - mu) * rstd * w[c0+256+3] + b[c0+256+3];
    *(float4*)(out + (size_t)row * D + c0) = r0;
    *(float4*)(out + (size_t)row * D + c0 + 256) = r1;
}

// ---------------- 128x64-tile bf16 GEMM, BK=64 double-buffered LDS ---------
// One barrier per chunk: stage chunk c+1 while computing chunk c.
struct GemmPtrs {
    const u16* A[6];
    const u16* Bt[6];
    const float* bias[6];
    void* C[6];
};

#define EPI_QKV  0   // bf16 store; pidx%3==2 -> store transposed into [D][T]
#define EPI_GELU 1   // bf16 store with exact gelu
#define EPI_PART 2   // bf16 store to partial buffer C + kc*M*N

template <int EPI>
__global__ __launch_bounds__(256) void gemm_kernel(GemmPtrs p, int M, int N, int K, int KS) {
    __shared__ __align__(16) u16 lA[2][128 * 64];
    __shared__ __align__(16) u16 lB[2][64 * 64];
    int nchunk = K / KS;
    int pidx = blockIdx.z / nchunk;
    int kc = blockIdx.z % nchunk;
    int koff = kc * KS;
    const u16* A = p.A[pidx];
    const u16* Bt = p.Bt[pidx];
    int m0 = blockIdx.y * 128, n0 = blockIdx.x * 64;
    int tid = threadIdx.x;
    int lane = tid & 63, wave = tid >> 6;
    int wx = wave & 1, wy = wave >> 1;
    int l16 = lane & 15, q4 = lane >> 4;
    // staging for BK=64: A tile 128x64 (2 row-groups of 64), B tile 64x64.
    // thread covers row = tid>>3 (0..31) x4 groups? Use: row=tid>>3, col=(tid&7)*8
    // A: 128 rows x 64 cols = 8192 el = 256 thr x 32 el -> 2 lds16 per rowgroup.
    const u16* ag = A + (size_t)(m0 + (tid >> 3)) * K + koff + (tid & 7) * 8;
    const u16* bg = Bt + (size_t)(n0 + (tid >> 3)) * K + koff + (tid & 7) * 8;
    size_t rskip32 = (size_t)32 * K;
    floatx4 acc[4][2] = {};
    int nch = KS / 64;
    // stage chunk 0 into buf 0: A rows tid>>3 + {0,32,64,96}, B rows tid>>3 + {0,32}
    {
#pragma unroll
        for (int g = 0; g < 4; g++)
            load_lds16(ag + g * rskip32, &lA[0][g * (32 * 64) + tid * 8]);
#pragma unroll
        for (int g = 0; g < 2; g++)
            load_lds16(bg + g * rskip32, &lB[0][g * (32 * 64) + tid * 8]);
    }
    __syncthreads();
    for (int c = 0; c < nch; c++) {
        int b = c & 1;
        if (c + 1 < nch) {
            int k0 = (c + 1) * 64;
#pragma unroll
            for (int g = 0; g < 4; g++)
                load_lds16(ag + g * rskip32 + k0, &lA[b ^ 1][g * (32 * 64) + tid * 8]);
#pragma unroll
            for (int g = 0; g < 2; g++)
                load_lds16(bg + g * rskip32 + k0, &lB[b ^ 1][g * (32 * 64) + tid * 8]);
        }
        // LDS layout: row-groups of 32 rows, each row 64 u16 contiguous.
        // row r (0..127) lives at lA[b][(r>>5)*(32*64) + (r&31)*64 + col].
#pragma unroll
        for (int kh = 0; kh < 2; kh++) {
            shortx8 af[4], bf[2];
#pragma unroll
            for (int t = 0; t < 4; t++) {
                int r = wy * 64 + t * 16 + l16;
                af[t] = *(const shortx8*)(&lA[b][(r >> 5) * (32 * 64) + (r & 31) * 64 + kh * 32 + q4 * 8]);
            }
#pragma unroll
            for (int t = 0; t < 2; t++) {
                int r = wx * 32 + t * 16 + l16;
                bf[t] = *(const shortx8*)(&lB[b][(r >> 5) * (32 * 64) + (r & 31) * 64 + kh * 32 + q4 * 8]);
            }
#pragma unroll
            for (int i = 0; i < 4; i++)
#pragma unroll
                for (int j = 0; j < 2; j++)
                    acc[i][j] = __builtin_amdgcn_mfma_f32_16x16x32_bf16(af[i], bf[j], acc[i][j], 0, 0, 0);
        }
        __syncthreads();
    }
    const float* bias = p.bias[pidx];
    bool vtrans = (EPI == EPI_QKV) && (pidx % 3 == 2);
#pragma unroll
    for (int i = 0; i < 4; i++) {
        int row0 = m0 + wy * 64 + i * 16 + q4 * 4;
#pragma unroll
        for (int j = 0; j < 2; j++) {
            int col = n0 + wx * 32 + j * 16 + l16;
            float bz = (kc == 0) ? bias[col] : 0.0f;
            floatx4 a = acc[i][j];
            if (EPI == EPI_QKV) {
                if (vtrans) {
                    u16x4 pk;
#pragma unroll
                    for (int r = 0; r < 4; r++) pk[r] = f2bf(a[r] + bz);
                    *(u16x4*)((u16*)p.C[pidx] + (size_t)col * M + row0) = pk;
                } else {
#pragma unroll
                    for (int r = 0; r < 4; r++)
                        ((u16*)p.C[pidx])[(size_t)(row0 + r) * N + col] = f2bf(a[r] + bz);
                }
            } else if (EPI == EPI_GELU) {
#pragma unroll
                for (int r = 0; r < 4; r++) {
                    float v = a[r] + bz;
                    float g = 0.5f * v * (1.0f + erff(v * 0.70710678118f));
                    ((u16*)p.C[pidx])[(size_t)(row0 + r) * N + col] = f2bf(g);
                }
            } else {
#pragma unroll
                for (int r = 0; r < 4; r++)
                    ((u16*)p.C[pidx])[(size_t)kc * M * N + (size_t)(row0 + r) * N + col] = f2bf(a[r] + bz);
            }
        }
    }
}

// ---------------- banded flash attention, in-WG split-K, no online max -----
__global__ __launch_bounds__(256) void attn_kernel(const u16* __restrict__ qg,
                                                   const u16* __restrict__ kg,
                                                   const u16* __restrict__ vtg,
                                                   u16* __restrict__ ao,
                                                   int bw0, int bw1) {
    __shared__ __align__(16) u16 pbuf[4][16 * 32];
    __shared__ float cl[4][16];
    __shared__ float co[4][16][64];
    int s = blockIdx.z, hh = blockIdx.y, q0 = blockIdx.x * 16;
    int bw = (s == 0) ? bw0 : bw1;
    int tid = threadIdx.x, wave = tid >> 6, lane = tid & 63;
    int l16 = lane & 15, q4 = lane >> 4;
    const u16* Q = qg + (size_t)s * T * D;
    const u16* Kp = kg + (size_t)s * T * D;
    const u16* V = vtg + (size_t)s * D * T;
    int hd = hh * DH;
    shortx8 qf0 = *(const shortx8*)(Q + (size_t)(q0 + l16) * D + hd + q4 * 8);
    shortx8 qf1 = *(const shortx8*)(Q + (size_t)(q0 + l16) * D + hd + 32 + q4 * 8);
    floatx4 o[4] = {};
    float lsum[4] = {};
    int klo = q0 - bw; if (klo < 0) klo = 0; klo &= ~31;
    int khi = q0 + 15;
    u16* pw = pbuf[wave];
    for (int kt = klo + wave * 32; kt <= khi; kt += 128) {
        floatx4 s0 = {}, s1 = {};
        {
            shortx8 kf0 = *(const shortx8*)(Kp + (size_t)(kt + l16) * D + hd + q4 * 8);
            shortx8 kf1 = *(const shortx8*)(Kp + (size_t)(kt + l16) * D + hd + 32 + q4 * 8);
            s0 = __builtin_amdgcn_mfma_f32_16x16x32_bf16(qf0, kf0, s0, 0, 0, 0);
            s0 = __builtin_amdgcn_mfma_f32_16x16x32_bf16(qf1, kf1, s0, 0, 0, 0);
            shortx8 kf2 = *(const shortx8*)(Kp + (size_t)(kt + 16 + l16) * D + hd + q4 * 8);
            shortx8 kf3 = *(const shortx8*)(Kp + (size_t)(kt + 16 + l16) * D + hd + 32 + q4 * 8);
            s1 = __builtin_amdgcn_mfma_f32_16x16x32_bf16(qf0, kf2, s1, 0, 0, 0);
            s1 = __builtin_amdgcn_mfma_f32_16x16x32_bf16(qf1, kf3, s1, 0, 0, 0);
        }
#pragma unroll
        for (int r = 0; r < 4; r++) {
            int row = q0 + q4 * 4 + r;
            int c0 = kt + l16, c1 = kt + 16 + l16;
            float p0 = (c0 <= row && c0 >= row - bw) ? __expf(s0[r] * 0.125f) : 0.0f;
            float p1 = (c1 <= row && c1 >= row - bw) ? __expf(s1[r] * 0.125f) : 0.0f;
            float ps = p0 + p1;
#pragma unroll
            for (int d2 = 1; d2 < 16; d2 <<= 1) ps += __shfl_xor(ps, d2);
            lsum[r] += ps;
            pw[(q4 * 4 + r) * 32 + l16] = f2bf(p0);
            pw[(q4 * 4 + r) * 32 + 16 + l16] = f2bf(p1);
        }
        shortx8 pf = *(const shortx8*)(pw + l16 * 32 + q4 * 8);
#pragma unroll
        for (int n = 0; n < 4; n++) {
            shortx8 vf = *(const shortx8*)(V + (size_t)(hd + n * 16 + l16) * T + kt + q4 * 8);
            o[n] = __builtin_amdgcn_mfma_f32_16x16x32_bf16(pf, vf, o[n], 0, 0, 0);
        }
    }
    if (l16 == 0) {
#pragma unroll
        for (int r = 0; r < 4; r++) cl[wave][q4 * 4 + r] = lsum[r];
    }
#pragma unroll
    for (int n = 0; n < 4; n++)
#pragma unroll
        for (int r = 0; r < 4; r++)
            co[wave][q4 * 4 + r][n * 16 + l16] = o[n][r];
    __syncthreads();
#pragma unroll
    for (int i = 0; i < 4; i++) {
        int idx = tid + i * 256;
        int row = idx >> 6, col = idx & 63;
        float Ls = cl[0][row] + cl[1][row] + cl[2][row] + cl[3][row];
        float O = co[0][row][col] + co[1][row][col] + co[2][row][col] + co[3][row][col];
        ao[(size_t)s * T * D + (size_t)(q0 + row) * D + hd + col] = f2bf(O / Ls);
    }
}

// ---------------------------------------------------------------------------
extern "C" void kernel_launch(void* const* d_in, const int* in_sizes, int n_in,
                              void* d_out, int out_size, void* d_ws, size_t ws_size,
                              hipStream_t stream) {
    (void)in_sizes; (void)n_in; (void)out_size; (void)ws_size;
    const float* x     = (const float*)d_in[0];
    const float* pos   = (const float*)d_in[1];
    const float* ln1_w = (const float*)d_in[2];
    const float* ln1_b = (const float*)d_in[3];
    const float* ln2_w = (const float*)d_in[4];
    const float* ln2_b = (const float*)d_in[5];
    const float* Wq    = (const float*)d_in[6];
    const float* bq    = (const float*)d_in[7];
    const float* Wk    = (const float*)d_in[8];
    const float* bk    = (const float*)d_in[9];
    const float* Wv    = (const float*)d_in[10];
    const float* bv    = (const float*)d_in[11];
    const float* Wo    = (const float*)d_in[12];
    const float* bo    = (const float*)d_in[13];
    const float* W1    = (const float*)d_in[14];
    const float* b1    = (const float*)d_in[15];
    const float* W2    = (const float*)d_in[16];
    const float* b2    = (const float*)d_in[17];
    const float* lnf_w = (const float*)d_in[18];
    const float* lnf_b = (const float*)d_in[19];

    char* ws = (char*)d_ws;
    size_t off = 0;
    auto alloc = [&](size_t bytes) { void* p = ws + off; off += (bytes + 255) & ~(size_t)255; return p; };
    u16* WqT = (u16*)alloc((size_t)4 * 512 * 512 * 2);
    u16* WkT = (u16*)alloc((size_t)4 * 512 * 512 * 2);
    u16* WvT = (u16*)alloc((size_t)4 * 512 * 512 * 2);
    u16* WoT = (u16*)alloc((size_t)4 * 512 * 512 * 2);
    u16* W1T = (u16*)alloc((size_t)4 * 512 * 1024 * 2);
    u16* W2T = (u16*)alloc((size_t)4 * 1024 * 512 * 2);
    float* h = (float*)alloc((size_t)2 * T * D * 4);
    u16* xln = (u16*)alloc((size_t)2 * T * D * 2);
    u16* qb  = (u16*)alloc((size_t)2 * T * D * 2);
    u16* kb  = (u16*)alloc((size_t)2 * T * D * 2);
    u16* vt  = (u16*)alloc((size_t)2 * T * D * 2);
    u16* ao  = (u16*)alloc((size_t)2 * T * D * 2);
    u16* ff  = (u16*)alloc((size_t)2 * T * 1024 * 2);
    u16* pp = (u16*)alloc((size_t)2 * 4 * T * D * 2);  // proj partials bf16 [s][4][T][D]
    u16* pf = (u16*)alloc((size_t)2 * 4 * T * D * 2);  // ff2 partials bf16

    TransJobs tj;
    tj.src[0] = Wq; tj.dst[0] = WqT;
    tj.src[1] = Wk; tj.dst[1] = WkT;
    tj.src[2] = Wv; tj.dst[2] = WvT;
    tj.src[3] = Wo; tj.dst[3] = WoT;
    tj.src[4] = W1; tj.dst[4] = W1T;
    tj.src[5] = W2; tj.dst[5] = W2T;
    tj.x = x; tj.pos = pos; tj.h = h;
    pre_kernel<<<dim3(32, 32, 25), 256, 0, stream>>>(tj);

    for (int l = 0; l < L; l++) {
        ln_res_kernel<<<(2 * T) / 4, 256, 0, stream>>>(h, l == 0 ? nullptr : pf,
                                                       ln1_w, ln1_b, xln, l);

        GemmPtrs g{};
        for (int s = 0; s < 2; s++) {
            int wo = s * L + l;
            const u16* a = xln + (size_t)s * T * D;
            g.A[s * 3 + 0] = a; g.Bt[s * 3 + 0] = WqT + (size_t)wo * 512 * 512;
            g.bias[s * 3 + 0] = bq + (size_t)wo * 512; g.C[s * 3 + 0] = qb + (size_t)s * T * D;
            g.A[s * 3 + 1] = a; g.Bt[s * 3 + 1] = WkT + (size_t)wo * 512 * 512;
            g.bias[s * 3 + 1] = bk + (size_t)wo * 512; g.C[s * 3 + 1] = kb + (size_t)s * T * D;
            g.A[s * 3 + 2] = a; g.Bt[s * 3 + 2] = WvT + (size_t)wo * 512 * 512;
            g.bias[s * 3 + 2] = bv + (size_t)wo * 512; g.C[s * 3 + 2] = vt + (size_t)s * T * D;
        }
        gemm_kernel<EPI_QKV><<<dim3(8, 16, 6), 256, 0, stream>>>(g, T, 512, 512, 512);

        attn_kernel<<<dim3(128, 8, 2), 256, 0, stream>>>(qb, kb, vt, ao, 999, 9);

        GemmPtrs gp{};
        for (int s = 0; s < 2; s++) {
            int wo = s * L + l;
            gp.A[s] = ao + (size_t)s * T * D;
            gp.Bt[s] = WoT + (size_t)wo * 512 * 512;
            gp.bias[s] = bo + (size_t)wo * 512;
            gp.C[s] = pp + (size_t)s * 4 * T * D;
        }
        gemm_kernel<EPI_PART><<<dim3(8, 16, 8), 256, 0, stream>>>(gp, T, 512, 512, 128);

        ln_res_kernel<<<(2 * T) / 4, 256, 0, stream>>>(h, pp, ln2_w, ln2_b, xln, l);

        GemmPtrs g1{};
        for (int s = 0; s < 2; s++) {
            int wo = s * L + l;
            g1.A[s] = xln + (size_t)s * T * D;
            g1.Bt[s] = W1T + (size_t)wo * 512 * 1024;
            g1.bias[s] = b1 + (size_t)wo * 1024;
            g1.C[s] = ff + (size_t)s * T * 1024;
        }
        gemm_kernel<EPI_GELU><<<dim3(16, 16, 2), 256, 0, stream>>>(g1, T, 1024, 512, 512);

        GemmPtrs g2{};
        for (int s = 0; s < 2; s++) {
            int wo = s * L + l;
            g2.A[s] = ff + (size_t)s * T * 1024;
            g2.Bt[s] = W2T + (size_t)wo * 1024 * 512;
            g2.bias[s] = b2 + (size_t)wo * 512;
            g2.C[s] = pf + (size_t)s * 4 * T * D;
        }
        gemm_kernel<EPI_PART><<<dim3(8, 16, 8), 256, 0, stream>>>(g2, T, 512, 1024, 256);
    }

    lnf_kernel<<<(2 * T) / 4, 256, 0, stream>>>(h, pf, lnf_w, lnf_b, (float*)d_out);
}

// Round 10
// 336.975 us; speedup vs baseline: 1.0540x; 1.0540x over previous
//
#include <hip/hip_runtime.h>
#include <stdint.h>

#define T 2048
#define D 512
#define NH 8
#define DH 64
#define L 2

typedef float floatx4 __attribute__((ext_vector_type(4)));
typedef short shortx8 __attribute__((ext_vector_type(8)));
typedef unsigned short u16;
typedef unsigned short u16x4 __attribute__((ext_vector_type(4)));

__device__ __forceinline__ u16 f2bf(float f) {
    union { float f; uint32_t u; } c; c.f = f;
    uint32_t u = c.u;
    u += 0x7fffu + ((u >> 16) & 1u);
    return (u16)(u >> 16);
}

__device__ __forceinline__ float bf2f(u16 v) {
    union { uint32_t u; float f; } c; c.u = ((uint32_t)v) << 16;
    return c.f;
}

__device__ __forceinline__ void load_lds16(const void* g, void* l) {
    __builtin_amdgcn_global_load_lds((const __attribute__((address_space(1))) void*)g,
                                     (__attribute__((address_space(3))) void*)l,
                                     16, 0, 0);
}

// ---------------- pre: weight transposes (z<24) + add_pos (z==24) ----------
struct TransJobs {
    const float* src[6];
    u16* dst[6];
    const float* x;
    const float* pos;
    float* h;
};

__global__ __launch_bounds__(256) void pre_kernel(TransJobs j) {
    __shared__ float tile[32][33];
    int tid = threadIdx.x;
    if (blockIdx.z == 24) {
        int idx = (blockIdx.y * 32 + blockIdx.x) * 256 + tid;
        float4 xv = ((const float4*)j.x)[idx];
        float4 pv = ((const float4*)j.pos)[idx];
        float4 r;
        r.x = xv.x + pv.x; r.y = xv.y + pv.y; r.z = xv.z + pv.z; r.w = xv.w + pv.w;
        ((float4*)j.h)[idx] = r;
        ((float4*)j.h)[idx + (T * D / 4)] = r;
        return;
    }
    int m = blockIdx.z >> 2, slice = blockIdx.z & 3;
    int R = (m == 5) ? 1024 : 512;
    int C = (m == 4) ? 1024 : 512;
    if (blockIdx.x * 32 >= C || blockIdx.y * 32 >= R) return;
    const float* in = j.src[m] + (size_t)slice * R * C;
    u16* out = j.dst[m] + (size_t)slice * R * C;
    int tx = tid & 31, ty = tid >> 5;
    int x = blockIdx.x * 32 + tx;
    int y0 = blockIdx.y * 32;
#pragma unroll
    for (int i = 0; i < 4; i++)
        tile[ty + i * 8][tx] = in[(size_t)(y0 + ty + i * 8) * C + x];
    __syncthreads();
    int ox = y0 + tx;
#pragma unroll
    for (int i = 0; i < 4; i++)
        out[(size_t)(blockIdx.x * 32 + ty + i * 8) * R + ox] = f2bf(tile[tx][ty + i * 8]);
}

// ---------------- LayerNorm + optional bf16-partial fold -------------------
__global__ __launch_bounds__(256) void ln_res_kernel(float* __restrict__ h,
                                                     const u16* __restrict__ part,
                                                     const float* __restrict__ w0,
                                                     const float* __restrict__ b0,
                                                     u16* __restrict__ out, int l) {
    int row = blockIdx.x * 4 + (threadIdx.x >> 6);
    int lane = threadIdx.x & 63;
    int s = row >> 11;
    int c0 = lane * 4;
    float* xr = h + (size_t)row * D;
    float4 v0 = *(const float4*)(xr + c0);
    float4 v1 = *(const float4*)(xr + c0 + 256);
    if (part) {
        const u16* p0r = part + (size_t)s * 2 * T * D + (size_t)(row & (T - 1)) * D;
        const u16* p1r = p0r + (size_t)T * D;
        u16x4 a0 = *(const u16x4*)(p0r + c0), a1 = *(const u16x4*)(p0r + c0 + 256);
        u16x4 e0 = *(const u16x4*)(p1r + c0), e1 = *(const u16x4*)(p1r + c0 + 256);
        v0.x += bf2f(a0[0]) + bf2f(e0[0]); v0.y += bf2f(a0[1]) + bf2f(e0[1]);
        v0.z += bf2f(a0[2]) + bf2f(e0[2]); v0.w += bf2f(a0[3]) + bf2f(e0[3]);
        v1.x += bf2f(a1[0]) + bf2f(e1[0]); v1.y += bf2f(a1[1]) + bf2f(e1[1]);
        v1.z += bf2f(a1[2]) + bf2f(e1[2]); v1.w += bf2f(a1[3]) + bf2f(e1[3]);
        *(float4*)(xr + c0) = v0;
        *(float4*)(xr + c0 + 256) = v1;
    }
    float sum = v0.x + v0.y + v0.z + v0.w + v1.x + v1.y + v1.z + v1.w;
    float sq = v0.x*v0.x + v0.y*v0.y + v0.z*v0.z + v0.w*v0.w
             + v1.x*v1.x + v1.y*v1.y + v1.z*v1.z + v1.w*v1.w;
#pragma unroll
    for (int d2 = 1; d2 < 64; d2 <<= 1) { sum += __shfl_xor(sum, d2); sq += __shfl_xor(sq, d2); }
    float mu = sum * (1.0f / D);
    float var = sq * (1.0f / D) - mu * mu;
    float rstd = rsqrtf(var + 1e-5f);
    const float* w = w0 + (size_t)(s * L + l) * D;
    const float* b = b0 + (size_t)(s * L + l) * D;
    u16x4 p0, p1;
#pragma unroll
    for (int jj = 0; jj < 4; jj++) {
        float a = (jj == 0 ? v0.x : jj == 1 ? v0.y : jj == 2 ? v0.z : v0.w);
        p0[jj] = f2bf((a - mu) * rstd * w[c0 + jj] + b[c0 + jj]);
        float c = (jj == 0 ? v1.x : jj == 1 ? v1.y : jj == 2 ? v1.z : v1.w);
        p1[jj] = f2bf((c - mu) * rstd * w[c0 + 256 + jj] + b[c0 + 256 + jj]);
    }
    *(u16x4*)(out + (size_t)row * D + c0) = p0;
    *(u16x4*)(out + (size_t)row * D + c0 + 256) = p1;
}

// ---------------- Final LayerNorm (+ bf16 partial fold) -> fp32 out --------
__global__ __launch_bounds__(256) void lnf_kernel(const float* __restrict__ h,
                                                  const u16* __restrict__ part,
                                                  const float* __restrict__ w,
                                                  const float* __restrict__ b,
                                                  float* __restrict__ out) {
    int row = blockIdx.x * 4 + (threadIdx.x >> 6);
    int lane = threadIdx.x & 63;
    int s = row >> 11;
    int c0 = lane * 4;
    const float* xr = h + (size_t)row * D;
    float4 v0 = *(const float4*)(xr + c0);
    float4 v1 = *(const float4*)(xr + c0 + 256);
    const u16* p0r = part + (size_t)s * 2 * T * D + (size_t)(row & (T - 1)) * D;
    const u16* p1r = p0r + (size_t)T * D;
    u16x4 a0 = *(const u16x4*)(p0r + c0), a1 = *(const u16x4*)(p0r + c0 + 256);
    u16x4 e0 = *(const u16x4*)(p1r + c0), e1 = *(const u16x4*)(p1r + c0 + 256);
    v0.x += bf2f(a0[0]) + bf2f(e0[0]); v0.y += bf2f(a0[1]) + bf2f(e0[1]);
    v0.z += bf2f(a0[2]) + bf2f(e0[2]); v0.w += bf2f(a0[3]) + bf2f(e0[3]);
    v1.x += bf2f(a1[0]) + bf2f(e1[0]); v1.y += bf2f(a1[1]) + bf2f(e1[1]);
    v1.z += bf2f(a1[2]) + bf2f(e1[2]); v1.w += bf2f(a1[3]) + bf2f(e1[3]);
    float sum = v0.x + v0.y + v0.z + v0.w + v1.x + v1.y + v1.z + v1.w;
    float sq = v0.x*v0.x + v0.y*v0.y + v0.z*v0.z + v0.w*v0.w
             + v1.x*v1.x + v1.y*v1.y + v1.z*v1.z + v1.w*v1.w;
#pragma unroll
    for (int d2 = 1; d2 < 64; d2 <<= 1) { sum += __shfl_xor(sum, d2); sq += __shfl_xor(sq, d2); }
    float mu = sum * (1.0f / D);
    float var = sq * (1.0f / D) - mu * mu;
    float rstd = rsqrtf(var + 1e-5f);
    float4 r0, r1;
    r0.x = (v0.x - mu) * rstd * w[c0+0] + b[c0+0];
    r0.y = (v0.y - mu) * rstd * w[c0+1] + b[c0+1];
    r0.z = (v0.z - mu) * rstd * w[c0+2] + b[c0+2];
    r0.w = (v0.w - mu) * rstd * w[c0+3] + b[c0+3];
    r1.x = (v1.x - mu) * rstd * w[c0+256+0] + b[c0+256+0];
    r1.y = (v1.y - mu) * rstd * w[c0+256+1] + b[c0+256+1];
    r1.z = (v1.z - mu) * rstd * w[c0+256+2] + b[c0+256+2];
    r1.w = (v1.w - mu) * rstd * w[c0+256+3] + b[c0+256+3];
    *(float4*)(out + (size_t)row * D + c0) = r0;
    *(float4*)(out + (size_t)row * D + c0 + 256) = r1;
}

// ---------------- 128x64-tile bf16 GEMM, BK=64 (LDS, global_load_lds) ------
struct GemmPtrs {
    const u16* A[6];
    const u16* Bt[6];
    const float* bias[6];
    void* C[6];
};

#define EPI_QKV  0   // bf16 store; pidx%3==2 -> store transposed into [D][T]
#define EPI_GELU 1   // bf16 store with exact gelu
#define EPI_PART 2   // bf16 store to partial buffer C + kc*M*N

template <int EPI>
__global__ __launch_bounds__(256) void gemm_kernel(GemmPtrs p, int M, int N, int K, int KS) {
    __shared__ __align__(16) u16 lA[2][128 * 32];
    __shared__ __align__(16) u16 lB[2][64 * 32];
    int nchunk = K / KS;
    int pidx = blockIdx.z / nchunk;
    int kc = blockIdx.z % nchunk;
    int koff = kc * KS;
    const u16* A = p.A[pidx];
    const u16* Bt = p.Bt[pidx];
    int m0 = blockIdx.y * 128, n0 = blockIdx.x * 64;
    int tid = threadIdx.x;
    int lane = tid & 63, wave = tid >> 6;
    int wx = wave & 1, wy = wave >> 1;
    int l16 = lane & 15, q4 = lane >> 4;
    const u16* ag = A + (size_t)(m0 + (tid >> 2)) * K + koff + (tid & 3) * 8;
    const u16* bg = Bt + (size_t)(n0 + (tid >> 2)) * K + koff + (tid & 3) * 8;
    size_t rowskip = (size_t)64 * K;
    floatx4 acc[4][2] = {};
    for (int k0 = 0; k0 < KS; k0 += 64) {
        __syncthreads();
#pragma unroll
        for (int kh = 0; kh < 2; kh++) {
            load_lds16(ag + k0 + kh * 32, &lA[kh][tid * 8]);
            load_lds16(ag + rowskip + k0 + kh * 32, &lA[kh][64 * 32 + tid * 8]);
            load_lds16(bg + k0 + kh * 32, &lB[kh][tid * 8]);
        }
        __syncthreads();
#pragma unroll
        for (int kh = 0; kh < 2; kh++) {
            shortx8 af[4], bf[2];
#pragma unroll
            for (int t = 0; t < 4; t++)
                af[t] = *(const shortx8*)(&lA[kh][(wy * 64 + t * 16 + l16) * 32 + q4 * 8]);
#pragma unroll
            for (int t = 0; t < 2; t++)
                bf[t] = *(const shortx8*)(&lB[kh][(wx * 32 + t * 16 + l16) * 32 + q4 * 8]);
#pragma unroll
            for (int i = 0; i < 4; i++)
#pragma unroll
                for (int j = 0; j < 2; j++)
                    acc[i][j] = __builtin_amdgcn_mfma_f32_16x16x32_bf16(af[i], bf[j], acc[i][j], 0, 0, 0);
        }
    }
    const float* bias = p.bias[pidx];
    bool vtrans = (EPI == EPI_QKV) && (pidx % 3 == 2);
#pragma unroll
    for (int i = 0; i < 4; i++) {
        int row0 = m0 + wy * 64 + i * 16 + q4 * 4;
#pragma unroll
        for (int j = 0; j < 2; j++) {
            int col = n0 + wx * 32 + j * 16 + l16;
            float bz = (kc == 0) ? bias[col] : 0.0f;
            floatx4 a = acc[i][j];
            if (EPI == EPI_QKV) {
                if (vtrans) {
                    u16x4 pk;
#pragma unroll
                    for (int r = 0; r < 4; r++) pk[r] = f2bf(a[r] + bz);
                    *(u16x4*)((u16*)p.C[pidx] + (size_t)col * M + row0) = pk;
                } else {
#pragma unroll
                    for (int r = 0; r < 4; r++)
                        ((u16*)p.C[pidx])[(size_t)(row0 + r) * N + col] = f2bf(a[r] + bz);
                }
            } else if (EPI == EPI_GELU) {
#pragma unroll
                for (int r = 0; r < 4; r++) {
                    float v = a[r] + bz;
                    float g = 0.5f * v * (1.0f + erff(v * 0.70710678118f));
                    ((u16*)p.C[pidx])[(size_t)(row0 + r) * N + col] = f2bf(g);
                }
            } else {
#pragma unroll
                for (int r = 0; r < 4; r++)
                    ((u16*)p.C[pidx])[(size_t)kc * M * N + (size_t)(row0 + r) * N + col] = f2bf(a[r] + bz);
            }
        }
    }
}

// ---------------- banded flash attention, in-WG split-K, no online max -----
// lsum accumulated per-lane in the k-loop; single shuffle-reduce at the end.
__global__ __launch_bounds__(256) void attn_kernel(const u16* __restrict__ qg,
                                                   const u16* __restrict__ kg,
                                                   const u16* __restrict__ vtg,
                                                   u16* __restrict__ ao,
                                                   int bw0, int bw1) {
    __shared__ __align__(16) u16 pbuf[4][16 * 32];
    __shared__ float cl[4][16];
    __shared__ float co[4][16][64];
    int s = blockIdx.z, hh = blockIdx.y, q0 = blockIdx.x * 16;
    int bw = (s == 0) ? bw0 : bw1;
    int tid = threadIdx.x, wave = tid >> 6, lane = tid & 63;
    int l16 = lane & 15, q4 = lane >> 4;
    const u16* Q = qg + (size_t)s * T * D;
    const u16* Kp = kg + (size_t)s * T * D;
    const u16* V = vtg + (size_t)s * D * T;
    int hd = hh * DH;
    shortx8 qf0 = *(const shortx8*)(Q + (size_t)(q0 + l16) * D + hd + q4 * 8);
    shortx8 qf1 = *(const shortx8*)(Q + (size_t)(q0 + l16) * D + hd + 32 + q4 * 8);
    floatx4 o[4] = {};
    float lsum[4] = {};
    int klo = q0 - bw; if (klo < 0) klo = 0; klo &= ~31;
    int khi = q0 + 15;
    u16* pw = pbuf[wave];
    for (int kt = klo + wave * 32; kt <= khi; kt += 128) {
        floatx4 s0 = {}, s1 = {};
        {
            shortx8 kf0 = *(const shortx8*)(Kp + (size_t)(kt + l16) * D + hd + q4 * 8);
            shortx8 kf1 = *(const shortx8*)(Kp + (size_t)(kt + l16) * D + hd + 32 + q4 * 8);
            s0 = __builtin_amdgcn_mfma_f32_16x16x32_bf16(qf0, kf0, s0, 0, 0, 0);
            s0 = __builtin_amdgcn_mfma_f32_16x16x32_bf16(qf1, kf1, s0, 0, 0, 0);
            shortx8 kf2 = *(const shortx8*)(Kp + (size_t)(kt + 16 + l16) * D + hd + q4 * 8);
            shortx8 kf3 = *(const shortx8*)(Kp + (size_t)(kt + 16 + l16) * D + hd + 32 + q4 * 8);
            s1 = __builtin_amdgcn_mfma_f32_16x16x32_bf16(qf0, kf2, s1, 0, 0, 0);
            s1 = __builtin_amdgcn_mfma_f32_16x16x32_bf16(qf1, kf3, s1, 0, 0, 0);
        }
#pragma unroll
        for (int r = 0; r < 4; r++) {
            int row = q0 + q4 * 4 + r;
            int c0 = kt + l16, c1 = kt + 16 + l16;
            float p0 = (c0 <= row && c0 >= row - bw) ? __expf(s0[r] * 0.125f) : 0.0f;
            float p1 = (c1 <= row && c1 >= row - bw) ? __expf(s1[r] * 0.125f) : 0.0f;
            lsum[r] += p0 + p1;
            pw[(q4 * 4 + r) * 32 + l16] = f2bf(p0);
            pw[(q4 * 4 + r) * 32 + 16 + l16] = f2bf(p1);
        }
        shortx8 pf = *(const shortx8*)(pw + l16 * 32 + q4 * 8);
#pragma unroll
        for (int n = 0; n < 4; n++) {
            shortx8 vf = *(const shortx8*)(V + (size_t)(hd + n * 16 + l16) * T + kt + q4 * 8);
            o[n] = __builtin_amdgcn_mfma_f32_16x16x32_bf16(pf, vf, o[n], 0, 0, 0);
        }
    }
    // one reduce per row at the end (16-lane groups; xor bits 0..3 stay in-group)
#pragma unroll
    for (int r = 0; r < 4; r++) {
#pragma unroll
        for (int d2 = 1; d2 < 16; d2 <<= 1) lsum[r] += __shfl_xor(lsum[r], d2);
    }
    if (l16 == 0) {
#pragma unroll
        for (int r = 0; r < 4; r++) cl[wave][q4 * 4 + r] = lsum[r];
    }
#pragma unroll
    for (int n = 0; n < 4; n++)
#pragma unroll
        for (int r = 0; r < 4; r++)
            co[wave][q4 * 4 + r][n * 16 + l16] = o[n][r];
    __syncthreads();
#pragma unroll
    for (int i = 0; i < 4; i++) {
        int idx = tid + i * 256;
        int row = idx >> 6, col = idx & 63;
        float Ls = cl[0][row] + cl[1][row] + cl[2][row] + cl[3][row];
        float O = co[0][row][col] + co[1][row][col] + co[2][row][col] + co[3][row][col];
        ao[(size_t)s * T * D + (size_t)(q0 + row) * D + hd + col] = f2bf(O / Ls);
    }
}

// ---------------------------------------------------------------------------
extern "C" void kernel_launch(void* const* d_in, const int* in_sizes, int n_in,
                              void* d_out, int out_size, void* d_ws, size_t ws_size,
                              hipStream_t stream) {
    (void)in_sizes; (void)n_in; (void)out_size; (void)ws_size;
    const float* x     = (const float*)d_in[0];
    const float* pos   = (const float*)d_in[1];
    const float* ln1_w = (const float*)d_in[2];
    const float* ln1_b = (const float*)d_in[3];
    const float* ln2_w = (const float*)d_in[4];
    const float* ln2_b = (const float*)d_in[5];
    const float* Wq    = (const float*)d_in[6];
    const float* bq    = (const float*)d_in[7];
    const float* Wk    = (const float*)d_in[8];
    const float* bk    = (const float*)d_in[9];
    const float* Wv    = (const float*)d_in[10];
    const float* bv    = (const float*)d_in[11];
    const float* Wo    = (const float*)d_in[12];
    const float* bo    = (const float*)d_in[13];
    const float* W1    = (const float*)d_in[14];
    const float* b1    = (const float*)d_in[15];
    const float* W2    = (const float*)d_in[16];
    const float* b2    = (const float*)d_in[17];
    const float* lnf_w = (const float*)d_in[18];
    const float* lnf_b = (const float*)d_in[19];

    char* ws = (char*)d_ws;
    size_t off = 0;
    auto alloc = [&](size_t bytes) { void* p = ws + off; off += (bytes + 255) & ~(size_t)255; return p; };
    u16* WqT = (u16*)alloc((size_t)4 * 512 * 512 * 2);
    u16* WkT = (u16*)alloc((size_t)4 * 512 * 512 * 2);
    u16* WvT = (u16*)alloc((size_t)4 * 512 * 512 * 2);
    u16* WoT = (u16*)alloc((size_t)4 * 512 * 512 * 2);
    u16* W1T = (u16*)alloc((size_t)4 * 512 * 1024 * 2);
    u16* W2T = (u16*)alloc((size_t)4 * 1024 * 512 * 2);
    float* h = (float*)alloc((size_t)2 * T * D * 4);
    u16* xln = (u16*)alloc((size_t)2 * T * D * 2);
    u16* qb  = (u16*)alloc((size_t)2 * T * D * 2);
    u16* kb  = (u16*)alloc((size_t)2 * T * D * 2);
    u16* vt  = (u16*)alloc((size_t)2 * T * D * 2);
    u16* ao  = (u16*)alloc((size_t)2 * T * D * 2);
    u16* ff  = (u16*)alloc((size_t)2 * T * 1024 * 2);
    u16* pp = (u16*)alloc((size_t)2 * 2 * T * D * 2);  // proj partials bf16 [s][2][T][D]
    u16* pf = (u16*)alloc((size_t)2 * 2 * T * D * 2);  // ff2 partials bf16

    TransJobs tj;
    tj.src[0] = Wq; tj.dst[0] = WqT;
    tj.src[1] = Wk; tj.dst[1] = WkT;
    tj.src[2] = Wv; tj.dst[2] = WvT;
    tj.src[3] = Wo; tj.dst[3] = WoT;
    tj.src[4] = W1; tj.dst[4] = W1T;
    tj.src[5] = W2; tj.dst[5] = W2T;
    tj.x = x; tj.pos = pos; tj.h = h;
    pre_kernel<<<dim3(32, 32, 25), 256, 0, stream>>>(tj);

    for (int l = 0; l < L; l++) {
        ln_res_kernel<<<(2 * T) / 4, 256, 0, stream>>>(h, l == 0 ? nullptr : pf,
                                                       ln1_w, ln1_b, xln, l);

        GemmPtrs g{};
        for (int s = 0; s < 2; s++) {
            int wo = s * L + l;
            const u16* a = xln + (size_t)s * T * D;
            g.A[s * 3 + 0] = a; g.Bt[s * 3 + 0] = WqT + (size_t)wo * 512 * 512;
            g.bias[s * 3 + 0] = bq + (size_t)wo * 512; g.C[s * 3 + 0] = qb + (size_t)s * T * D;
            g.A[s * 3 + 1] = a; g.Bt[s * 3 + 1] = WkT + (size_t)wo * 512 * 512;
            g.bias[s * 3 + 1] = bk + (size_t)wo * 512; g.C[s * 3 + 1] = kb + (size_t)s * T * D;
            g.A[s * 3 + 2] = a; g.Bt[s * 3 + 2] = WvT + (size_t)wo * 512 * 512;
            g.bias[s * 3 + 2] = bv + (size_t)wo * 512; g.C[s * 3 + 2] = vt + (size_t)s * T * D;
        }
        gemm_kernel<EPI_QKV><<<dim3(8, 16, 6), 256, 0, stream>>>(g, T, 512, 512, 512);

        attn_kernel<<<dim3(128, 8, 2), 256, 0, stream>>>(qb, kb, vt, ao, 999, 9);

        GemmPtrs gp{};
        for (int s = 0; s < 2; s++) {
            int wo = s * L + l;
            gp.A[s] = ao + (size_t)s * T * D;
            gp.Bt[s] = WoT + (size_t)wo * 512 * 512;
            gp.bias[s] = bo + (size_t)wo * 512;
            gp.C[s] = pp + (size_t)s * 2 * T * D;
        }
        gemm_kernel<EPI_PART><<<dim3(8, 16, 4), 256, 0, stream>>>(gp, T, 512, 512, 256);

        ln_res_kernel<<<(2 * T) / 4, 256, 0, stream>>>(h, pp, ln2_w, ln2_b, xln, l);

        GemmPtrs g1{};
        for (int s = 0; s < 2; s++) {
            int wo = s * L + l;
            g1.A[s] = xln + (size_t)s * T * D;
            g1.Bt[s] = W1T + (size_t)wo * 512 * 1024;
            g1.bias[s] = b1 + (size_t)wo * 1024;
            g1.C[s] = ff + (size_t)s * T * 1024;
        }
        gemm_kernel<EPI_GELU><<<dim3(16, 16, 2), 256, 0, stream>>>(g1, T, 1024, 512, 512);

        GemmPtrs g2{};
        for (int s = 0; s < 2; s++) {
            int wo = s * L + l;
            g2.A[s] = ff + (size_t)s * T * 1024;
            g2.Bt[s] = W2T + (size_t)wo * 1024 * 512;
            g2.bias[s] = b2 + (size_t)wo * 512;
            g2.C[s] = pf + (size_t)s * 2 * T * D;
        }
        gemm_kernel<EPI_PART><<<dim3(8, 16, 4), 256, 0, stream>>>(g2, T, 512, 1024, 512);
    }

    lnf_kernel<<<(2 * T) / 4, 256, 0, stream>>>(h, pf, lnf_w, lnf_b, (float*)d_out);
}

// Round 11
// 327.763 us; speedup vs baseline: 1.0836x; 1.0281x over previous
//
#include <hip/hip_runtime.h>
#include <stdint.h>

#define T 2048
#define D 512
#define NH 8
#define DH 64
#define L 2

typedef float floatx4 __attribute__((ext_vector_type(4)));
typedef short shortx8 __attribute__((ext_vector_type(8)));
typedef unsigned short u16;
typedef unsigned short u16x4 __attribute__((ext_vector_type(4)));

__device__ __forceinline__ u16 f2bf(float f) {
    union { float f; uint32_t u; } c; c.f = f;
    uint32_t u = c.u;
    u += 0x7fffu + ((u >> 16) & 1u);
    return (u16)(u >> 16);
}

__device__ __forceinline__ float bf2f(u16 v) {
    union { uint32_t u; float f; } c; c.u = ((uint32_t)v) << 16;
    return c.f;
}

__device__ __forceinline__ void load_lds16(const void* g, void* l) {
    __builtin_amdgcn_global_load_lds((const __attribute__((address_space(1))) void*)g,
                                     (__attribute__((address_space(3))) void*)l,
                                     16, 0, 0);
}

// ---------------- pre: weight transposes (z<24) + add_pos (z==24) ----------
struct TransJobs {
    const float* src[6];
    u16* dst[6];
    const float* x;
    const float* pos;
    float* h;
};

__global__ __launch_bounds__(256) void pre_kernel(TransJobs j) {
    __shared__ float tile[32][33];
    int tid = threadIdx.x;
    if (blockIdx.z == 24) {
        int idx = (blockIdx.y * 32 + blockIdx.x) * 256 + tid;
        float4 xv = ((const float4*)j.x)[idx];
        float4 pv = ((const float4*)j.pos)[idx];
        float4 r;
        r.x = xv.x + pv.x; r.y = xv.y + pv.y; r.z = xv.z + pv.z; r.w = xv.w + pv.w;
        ((float4*)j.h)[idx] = r;
        ((float4*)j.h)[idx + (T * D / 4)] = r;
        return;
    }
    int m = blockIdx.z >> 2, slice = blockIdx.z & 3;
    int R = (m == 5) ? 1024 : 512;
    int C = (m == 4) ? 1024 : 512;
    if (blockIdx.x * 32 >= C || blockIdx.y * 32 >= R) return;
    const float* in = j.src[m] + (size_t)slice * R * C;
    u16* out = j.dst[m] + (size_t)slice * R * C;
    int tx = tid & 31, ty = tid >> 5;
    int x = blockIdx.x * 32 + tx;
    int y0 = blockIdx.y * 32;
#pragma unroll
    for (int i = 0; i < 4; i++)
        tile[ty + i * 8][tx] = in[(size_t)(y0 + ty + i * 8) * C + x];
    __syncthreads();
    int ox = y0 + tx;
#pragma unroll
    for (int i = 0; i < 4; i++)
        out[(size_t)(blockIdx.x * 32 + ty + i * 8) * R + ox] = f2bf(tile[tx][ty + i * 8]);
}

// ---------------- LayerNorm + optional bf16-partial fold -------------------
__global__ __launch_bounds__(256) void ln_res_kernel(float* __restrict__ h,
                                                     const u16* __restrict__ part,
                                                     const float* __restrict__ w0,
                                                     const float* __restrict__ b0,
                                                     u16* __restrict__ out, int l) {
    int row = blockIdx.x * 4 + (threadIdx.x >> 6);
    int lane = threadIdx.x & 63;
    int s = row >> 11;
    int c0 = lane * 4;
    float* xr = h + (size_t)row * D;
    float4 v0 = *(const float4*)(xr + c0);
    float4 v1 = *(const float4*)(xr + c0 + 256);
    if (part) {
        const u16* p0r = part + (size_t)s * 2 * T * D + (size_t)(row & (T - 1)) * D;
        const u16* p1r = p0r + (size_t)T * D;
        u16x4 a0 = *(const u16x4*)(p0r + c0), a1 = *(const u16x4*)(p0r + c0 + 256);
        u16x4 e0 = *(const u16x4*)(p1r + c0), e1 = *(const u16x4*)(p1r + c0 + 256);
        v0.x += bf2f(a0[0]) + bf2f(e0[0]); v0.y += bf2f(a0[1]) + bf2f(e0[1]);
        v0.z += bf2f(a0[2]) + bf2f(e0[2]); v0.w += bf2f(a0[3]) + bf2f(e0[3]);
        v1.x += bf2f(a1[0]) + bf2f(e1[0]); v1.y += bf2f(a1[1]) + bf2f(e1[1]);
        v1.z += bf2f(a1[2]) + bf2f(e1[2]); v1.w += bf2f(a1[3]) + bf2f(e1[3]);
        *(float4*)(xr + c0) = v0;
        *(float4*)(xr + c0 + 256) = v1;
    }
    float sum = v0.x + v0.y + v0.z + v0.w + v1.x + v1.y + v1.z + v1.w;
    float sq = v0.x*v0.x + v0.y*v0.y + v0.z*v0.z + v0.w*v0.w
             + v1.x*v1.x + v1.y*v1.y + v1.z*v1.z + v1.w*v1.w;
#pragma unroll
    for (int d2 = 1; d2 < 64; d2 <<= 1) { sum += __shfl_xor(sum, d2); sq += __shfl_xor(sq, d2); }
    float mu = sum * (1.0f / D);
    float var = sq * (1.0f / D) - mu * mu;
    float rstd = rsqrtf(var + 1e-5f);
    const float* w = w0 + (size_t)(s * L + l) * D;
    const float* b = b0 + (size_t)(s * L + l) * D;
    u16x4 p0, p1;
#pragma unroll
    for (int jj = 0; jj < 4; jj++) {
        float a = (jj == 0 ? v0.x : jj == 1 ? v0.y : jj == 2 ? v0.z : v0.w);
        p0[jj] = f2bf((a - mu) * rstd * w[c0 + jj] + b[c0 + jj]);
        float c = (jj == 0 ? v1.x : jj == 1 ? v1.y : jj == 2 ? v1.z : v1.w);
        p1[jj] = f2bf((c - mu) * rstd * w[c0 + 256 + jj] + b[c0 + 256 + jj]);
    }
    *(u16x4*)(out + (size_t)row * D + c0) = p0;
    *(u16x4*)(out + (size_t)row * D + c0 + 256) = p1;
}

// ---------------- Final LayerNorm (+ bf16 partial fold) -> fp32 out --------
__global__ __launch_bounds__(256) void lnf_kernel(const float* __restrict__ h,
                                                  const u16* __restrict__ part,
                                                  const float* __restrict__ w,
                                                  const float* __restrict__ b,
                                                  float* __restrict__ out) {
    int row = blockIdx.x * 4 + (threadIdx.x >> 6);
    int lane = threadIdx.x & 63;
    int s = row >> 11;
    int c0 = lane * 4;
    const float* xr = h + (size_t)row * D;
    float4 v0 = *(const float4*)(xr + c0);
    float4 v1 = *(const float4*)(xr + c0 + 256);
    const u16* p0r = part + (size_t)s * 2 * T * D + (size_t)(row & (T - 1)) * D;
    const u16* p1r = p0r + (size_t)T * D;
    u16x4 a0 = *(const u16x4*)(p0r + c0), a1 = *(const u16x4*)(p0r + c0 + 256);
    u16x4 e0 = *(const u16x4*)(p1r + c0), e1 = *(const u16x4*)(p1r + c0 + 256);
    v0.x += bf2f(a0[0]) + bf2f(e0[0]); v0.y += bf2f(a0[1]) + bf2f(e0[1]);
    v0.z += bf2f(a0[2]) + bf2f(e0[2]); v0.w += bf2f(a0[3]) + bf2f(e0[3]);
    v1.x += bf2f(a1[0]) + bf2f(e1[0]); v1.y += bf2f(a1[1]) + bf2f(e1[1]);
    v1.z += bf2f(a1[2]) + bf2f(e1[2]); v1.w += bf2f(a1[3]) + bf2f(e1[3]);
    float sum = v0.x + v0.y + v0.z + v0.w + v1.x + v1.y + v1.z + v1.w;
    float sq = v0.x*v0.x + v0.y*v0.y + v0.z*v0.z + v0.w*v0.w
             + v1.x*v1.x + v1.y*v1.y + v1.z*v1.z + v1.w*v1.w;
#pragma unroll
    for (int d2 = 1; d2 < 64; d2 <<= 1) { sum += __shfl_xor(sum, d2); sq += __shfl_xor(sq, d2); }
    float mu = sum * (1.0f / D);
    float var = sq * (1.0f / D) - mu * mu;
    float rstd = rsqrtf(var + 1e-5f);
    float4 r0, r1;
    r0.x = (v0.x - mu) * rstd * w[c0+0] + b[c0+0];
    r0.y = (v0.y - mu) * rstd * w[c0+1] + b[c0+1];
    r0.z = (v0.z - mu) * rstd * w[c0+2] + b[c0+2];
    r0.w = (v0.w - mu) * rstd * w[c0+3] + b[c0+3];
    r1.x = (v1.x - mu) * rstd * w[c0+256+0] + b[c0+256+0];
    r1.y = (v1.y - mu) * rstd * w[c0+256+1] + b[c0+256+1];
    r1.z = (v1.z - mu) * rstd * w[c0+256+2] + b[c0+256+2];
    r1.w = (v1.w - mu) * rstd * w[c0+256+3] + b[c0+256+3];
    *(float4*)(out + (size_t)row * D + c0) = r0;
    *(float4*)(out + (size_t)row * D + c0 + 256) = r1;
}

// ---------------- 64x64-tile bf16 GEMM, BK=64 (LDS, global_load_lds) -------
// Smaller tile -> 2x grid -> ~4-6 blocks/CU co-resident to overlap drains.
struct GemmPtrs {
    const u16* A[6];
    const u16* Bt[6];
    const float* bias[6];
    void* C[6];
};

#define EPI_QKV  0   // bf16 store; pidx%3==2 -> store transposed into [D][T]
#define EPI_GELU 1   // bf16 store with exact gelu
#define EPI_PART 2   // bf16 store to partial buffer C + kc*M*N

template <int EPI>
__global__ __launch_bounds__(256) void gemm_kernel(GemmPtrs p, int M, int N, int K, int KS) {
    __shared__ __align__(16) u16 lA[2][64 * 32];
    __shared__ __align__(16) u16 lB[2][64 * 32];
    int nchunk = K / KS;
    int pidx = blockIdx.z / nchunk;
    int kc = blockIdx.z % nchunk;
    int koff = kc * KS;
    const u16* A = p.A[pidx];
    const u16* Bt = p.Bt[pidx];
    int m0 = blockIdx.y * 64, n0 = blockIdx.x * 64;
    int tid = threadIdx.x;
    int lane = tid & 63, wave = tid >> 6;
    int wx = wave & 1, wy = wave >> 1;          // 2x2 wave grid, 32x32 each
    int l16 = lane & 15, q4 = lane >> 4;
    const u16* ag = A + (size_t)(m0 + (tid >> 2)) * K + koff + (tid & 3) * 8;
    const u16* bg = Bt + (size_t)(n0 + (tid >> 2)) * K + koff + (tid & 3) * 8;
    floatx4 acc[2][2] = {};
    for (int k0 = 0; k0 < KS; k0 += 64) {
        __syncthreads();
#pragma unroll
        for (int kh = 0; kh < 2; kh++) {
            load_lds16(ag + k0 + kh * 32, &lA[kh][tid * 8]);
            load_lds16(bg + k0 + kh * 32, &lB[kh][tid * 8]);
        }
        __syncthreads();
#pragma unroll
        for (int kh = 0; kh < 2; kh++) {
            shortx8 af[2], bf[2];
#pragma unroll
            for (int t = 0; t < 2; t++) {
                af[t] = *(const shortx8*)(&lA[kh][(wy * 32 + t * 16 + l16) * 32 + q4 * 8]);
                bf[t] = *(const shortx8*)(&lB[kh][(wx * 32 + t * 16 + l16) * 32 + q4 * 8]);
            }
#pragma unroll
            for (int i = 0; i < 2; i++)
#pragma unroll
                for (int j = 0; j < 2; j++)
                    acc[i][j] = __builtin_amdgcn_mfma_f32_16x16x32_bf16(af[i], bf[j], acc[i][j], 0, 0, 0);
        }
    }
    const float* bias = p.bias[pidx];
    bool vtrans = (EPI == EPI_QKV) && (pidx % 3 == 2);
#pragma unroll
    for (int i = 0; i < 2; i++) {
        int row0 = m0 + wy * 32 + i * 16 + q4 * 4;
#pragma unroll
        for (int j = 0; j < 2; j++) {
            int col = n0 + wx * 32 + j * 16 + l16;
            float bz = (kc == 0) ? bias[col] : 0.0f;
            floatx4 a = acc[i][j];
            if (EPI == EPI_QKV) {
                if (vtrans) {
                    u16x4 pk;
#pragma unroll
                    for (int r = 0; r < 4; r++) pk[r] = f2bf(a[r] + bz);
                    *(u16x4*)((u16*)p.C[pidx] + (size_t)col * M + row0) = pk;
                } else {
#pragma unroll
                    for (int r = 0; r < 4; r++)
                        ((u16*)p.C[pidx])[(size_t)(row0 + r) * N + col] = f2bf(a[r] + bz);
                }
            } else if (EPI == EPI_GELU) {
#pragma unroll
                for (int r = 0; r < 4; r++) {
                    float v = a[r] + bz;
                    float g = 0.5f * v * (1.0f + erff(v * 0.70710678118f));
                    ((u16*)p.C[pidx])[(size_t)(row0 + r) * N + col] = f2bf(g);
                }
            } else {
#pragma unroll
                for (int r = 0; r < 4; r++)
                    ((u16*)p.C[pidx])[(size_t)kc * M * N + (size_t)(row0 + r) * N + col] = f2bf(a[r] + bz);
            }
        }
    }
}

// ---------------- banded flash attention, in-WG split-K, no online max -----
__global__ __launch_bounds__(256) void attn_kernel(const u16* __restrict__ qg,
                                                   const u16* __restrict__ kg,
                                                   const u16* __restrict__ vtg,
                                                   u16* __restrict__ ao,
                                                   int bw0, int bw1) {
    __shared__ __align__(16) u16 pbuf[4][16 * 32];
    __shared__ float cl[4][16];
    __shared__ float co[4][16][64];
    int s = blockIdx.z, hh = blockIdx.y, q0 = blockIdx.x * 16;
    int bw = (s == 0) ? bw0 : bw1;
    int tid = threadIdx.x, wave = tid >> 6, lane = tid & 63;
    int l16 = lane & 15, q4 = lane >> 4;
    const u16* Q = qg + (size_t)s * T * D;
    const u16* Kp = kg + (size_t)s * T * D;
    const u16* V = vtg + (size_t)s * D * T;
    int hd = hh * DH;
    shortx8 qf0 = *(const shortx8*)(Q + (size_t)(q0 + l16) * D + hd + q4 * 8);
    shortx8 qf1 = *(const shortx8*)(Q + (size_t)(q0 + l16) * D + hd + 32 + q4 * 8);
    floatx4 o[4] = {};
    float lsum[4] = {};
    int klo = q0 - bw; if (klo < 0) klo = 0; klo &= ~31;
    int khi = q0 + 15;
    u16* pw = pbuf[wave];
    for (int kt = klo + wave * 32; kt <= khi; kt += 128) {
        floatx4 s0 = {}, s1 = {};
        {
            shortx8 kf0 = *(const shortx8*)(Kp + (size_t)(kt + l16) * D + hd + q4 * 8);
            shortx8 kf1 = *(const shortx8*)(Kp + (size_t)(kt + l16) * D + hd + 32 + q4 * 8);
            s0 = __builtin_amdgcn_mfma_f32_16x16x32_bf16(qf0, kf0, s0, 0, 0, 0);
            s0 = __builtin_amdgcn_mfma_f32_16x16x32_bf16(qf1, kf1, s0, 0, 0, 0);
            shortx8 kf2 = *(const shortx8*)(Kp + (size_t)(kt + 16 + l16) * D + hd + q4 * 8);
            shortx8 kf3 = *(const shortx8*)(Kp + (size_t)(kt + 16 + l16) * D + hd + 32 + q4 * 8);
            s1 = __builtin_amdgcn_mfma_f32_16x16x32_bf16(qf0, kf2, s1, 0, 0, 0);
            s1 = __builtin_amdgcn_mfma_f32_16x16x32_bf16(qf1, kf3, s1, 0, 0, 0);
        }
#pragma unroll
        for (int r = 0; r < 4; r++) {
            int row = q0 + q4 * 4 + r;
            int c0 = kt + l16, c1 = kt + 16 + l16;
            float p0 = (c0 <= row && c0 >= row - bw) ? __expf(s0[r] * 0.125f) : 0.0f;
            float p1 = (c1 <= row && c1 >= row - bw) ? __expf(s1[r] * 0.125f) : 0.0f;
            lsum[r] += p0 + p1;
            pw[(q4 * 4 + r) * 32 + l16] = f2bf(p0);
            pw[(q4 * 4 + r) * 32 + 16 + l16] = f2bf(p1);
        }
        shortx8 pf = *(const shortx8*)(pw + l16 * 32 + q4 * 8);
#pragma unroll
        for (int n = 0; n < 4; n++) {
            shortx8 vf = *(const shortx8*)(V + (size_t)(hd + n * 16 + l16) * T + kt + q4 * 8);
            o[n] = __builtin_amdgcn_mfma_f32_16x16x32_bf16(pf, vf, o[n], 0, 0, 0);
        }
    }
#pragma unroll
    for (int r = 0; r < 4; r++) {
#pragma unroll
        for (int d2 = 1; d2 < 16; d2 <<= 1) lsum[r] += __shfl_xor(lsum[r], d2);
    }
    if (l16 == 0) {
#pragma unroll
        for (int r = 0; r < 4; r++) cl[wave][q4 * 4 + r] = lsum[r];
    }
#pragma unroll
    for (int n = 0; n < 4; n++)
#pragma unroll
        for (int r = 0; r < 4; r++)
            co[wave][q4 * 4 + r][n * 16 + l16] = o[n][r];
    __syncthreads();
#pragma unroll
    for (int i = 0; i < 4; i++) {
        int idx = tid + i * 256;
        int row = idx >> 6, col = idx & 63;
        float Ls = cl[0][row] + cl[1][row] + cl[2][row] + cl[3][row];
        float O = co[0][row][col] + co[1][row][col] + co[2][row][col] + co[3][row][col];
        ao[(size_t)s * T * D + (size_t)(q0 + row) * D + hd + col] = f2bf(O / Ls);
    }
}

// ---------------------------------------------------------------------------
extern "C" void kernel_launch(void* const* d_in, const int* in_sizes, int n_in,
                              void* d_out, int out_size, void* d_ws, size_t ws_size,
                              hipStream_t stream) {
    (void)in_sizes; (void)n_in; (void)out_size; (void)ws_size;
    const float* x     = (const float*)d_in[0];
    const float* pos   = (const float*)d_in[1];
    const float* ln1_w = (const float*)d_in[2];
    const float* ln1_b = (const float*)d_in[3];
    const float* ln2_w = (const float*)d_in[4];
    const float* ln2_b = (const float*)d_in[5];
    const float* Wq    = (const float*)d_in[6];
    const float* bq    = (const float*)d_in[7];
    const float* Wk    = (const float*)d_in[8];
    const float* bk    = (const float*)d_in[9];
    const float* Wv    = (const float*)d_in[10];
    const float* bv    = (const float*)d_in[11];
    const float* Wo    = (const float*)d_in[12];
    const float* bo    = (const float*)d_in[13];
    const float* W1    = (const float*)d_in[14];
    const float* b1    = (const float*)d_in[15];
    const float* W2    = (const float*)d_in[16];
    const float* b2    = (const float*)d_in[17];
    const float* lnf_w = (const float*)d_in[18];
    const float* lnf_b = (const float*)d_in[19];

    char* ws = (char*)d_ws;
    size_t off = 0;
    auto alloc = [&](size_t bytes) { void* p = ws + off; off += (bytes + 255) & ~(size_t)255; return p; };
    u16* WqT = (u16*)alloc((size_t)4 * 512 * 512 * 2);
    u16* WkT = (u16*)alloc((size_t)4 * 512 * 512 * 2);
    u16* WvT = (u16*)alloc((size_t)4 * 512 * 512 * 2);
    u16* WoT = (u16*)alloc((size_t)4 * 512 * 512 * 2);
    u16* W1T = (u16*)alloc((size_t)4 * 512 * 1024 * 2);
    u16* W2T = (u16*)alloc((size_t)4 * 1024 * 512 * 2);
    float* h = (float*)alloc((size_t)2 * T * D * 4);
    u16* xln = (u16*)alloc((size_t)2 * T * D * 2);
    u16* qb  = (u16*)alloc((size_t)2 * T * D * 2);
    u16* kb  = (u16*)alloc((size_t)2 * T * D * 2);
    u16* vt  = (u16*)alloc((size_t)2 * T * D * 2);
    u16* ao  = (u16*)alloc((size_t)2 * T * D * 2);
    u16* ff  = (u16*)alloc((size_t)2 * T * 1024 * 2);
    u16* pp = (u16*)alloc((size_t)2 * 2 * T * D * 2);  // proj partials bf16 [s][2][T][D]
    u16* pf = (u16*)alloc((size_t)2 * 2 * T * D * 2);  // ff2 partials bf16

    TransJobs tj;
    tj.src[0] = Wq; tj.dst[0] = WqT;
    tj.src[1] = Wk; tj.dst[1] = WkT;
    tj.src[2] = Wv; tj.dst[2] = WvT;
    tj.src[3] = Wo; tj.dst[3] = WoT;
    tj.src[4] = W1; tj.dst[4] = W1T;
    tj.src[5] = W2; tj.dst[5] = W2T;
    tj.x = x; tj.pos = pos; tj.h = h;
    pre_kernel<<<dim3(32, 32, 25), 256, 0, stream>>>(tj);

    for (int l = 0; l < L; l++) {
        ln_res_kernel<<<(2 * T) / 4, 256, 0, stream>>>(h, l == 0 ? nullptr : pf,
                                                       ln1_w, ln1_b, xln, l);

        GemmPtrs g{};
        for (int s = 0; s < 2; s++) {
            int wo = s * L + l;
            const u16* a = xln + (size_t)s * T * D;
            g.A[s * 3 + 0] = a; g.Bt[s * 3 + 0] = WqT + (size_t)wo * 512 * 512;
            g.bias[s * 3 + 0] = bq + (size_t)wo * 512; g.C[s * 3 + 0] = qb + (size_t)s * T * D;
            g.A[s * 3 + 1] = a; g.Bt[s * 3 + 1] = WkT + (size_t)wo * 512 * 512;
            g.bias[s * 3 + 1] = bk + (size_t)wo * 512; g.C[s * 3 + 1] = kb + (size_t)s * T * D;
            g.A[s * 3 + 2] = a; g.Bt[s * 3 + 2] = WvT + (size_t)wo * 512 * 512;
            g.bias[s * 3 + 2] = bv + (size_t)wo * 512; g.C[s * 3 + 2] = vt + (size_t)s * T * D;
        }
        gemm_kernel<EPI_QKV><<<dim3(8, 32, 6), 256, 0, stream>>>(g, T, 512, 512, 512);

        attn_kernel<<<dim3(128, 8, 2), 256, 0, stream>>>(qb, kb, vt, ao, 999, 9);

        GemmPtrs gp{};
        for (int s = 0; s < 2; s++) {
            int wo = s * L + l;
            gp.A[s] = ao + (size_t)s * T * D;
            gp.Bt[s] = WoT + (size_t)wo * 512 * 512;
            gp.bias[s] = bo + (size_t)wo * 512;
            gp.C[s] = pp + (size_t)s * 2 * T * D;
        }
        gemm_kernel<EPI_PART><<<dim3(8, 32, 4), 256, 0, stream>>>(gp, T, 512, 512, 256);

        ln_res_kernel<<<(2 * T) / 4, 256, 0, stream>>>(h, pp, ln2_w, ln2_b, xln, l);

        GemmPtrs g1{};
        for (int s = 0; s < 2; s++) {
            int wo = s * L + l;
            g1.A[s] = xln + (size_t)s * T * D;
            g1.Bt[s] = W1T + (size_t)wo * 512 * 1024;
            g1.bias[s] = b1 + (size_t)wo * 1024;
            g1.C[s] = ff + (size_t)s * T * 1024;
        }
        gemm_kernel<EPI_GELU><<<dim3(16, 32, 2), 256, 0, stream>>>(g1, T, 1024, 512, 512);

        GemmPtrs g2{};
        for (int s = 0; s < 2; s++) {
            int wo = s * L + l;
            g2.A[s] = ff + (size_t)s * T * 1024;
            g2.Bt[s] = W2T + (size_t)wo * 1024 * 512;
            g2.bias[s] = b2 + (size_t)wo * 512;
            g2.C[s] = pf + (size_t)s * 2 * T * D;
        }
        gemm_kernel<EPI_PART><<<dim3(8, 32, 4), 256, 0, stream>>>(g2, T, 512, 1024, 512);
    }

    lnf_kernel<<<(2 * T) / 4, 256, 0, stream>>>(h, pf, lnf_w, lnf_b, (float*)d_out);
}

// Round 12
// 319.579 us; speedup vs baseline: 1.1114x; 1.0256x over previous
//
#include <hip/hip_runtime.h>
#include <stdint.h>

#define T 2048
#define D 512
#define NH 8
#define DH 64
#define L 2

typedef float floatx4 __attribute__((ext_vector_type(4)));
typedef short shortx8 __attribute__((ext_vector_type(8)));
typedef unsigned short u16;
typedef unsigned short u16x4 __attribute__((ext_vector_type(4)));

__device__ __forceinline__ u16 f2bf(float f) {
    union { float f; uint32_t u; } c; c.f = f;
    uint32_t u = c.u;
    u += 0x7fffu + ((u >> 16) & 1u);
    return (u16)(u >> 16);
}

__device__ __forceinline__ float bf2f(u16 v) {
    union { uint32_t u; float f; } c; c.u = ((uint32_t)v) << 16;
    return c.f;
}

__device__ __forceinline__ void load_lds16(const void* g, void* l) {
    __builtin_amdgcn_global_load_lds((const __attribute__((address_space(1))) void*)g,
                                     (__attribute__((address_space(3))) void*)l,
                                     16, 0, 0);
}

// ---------------- pre: weight transposes (z<24) + add_pos (z==24) ----------
struct TransJobs {
    const float* src[6];
    u16* dst[6];
    const float* x;
    const float* pos;
    u16* h;
};

__global__ __launch_bounds__(256) void pre_kernel(TransJobs j) {
    __shared__ float tile[32][33];
    int tid = threadIdx.x;
    if (blockIdx.z == 24) {
        int idx = (blockIdx.y * 32 + blockIdx.x) * 256 + tid;  // float4 index
        float4 xv = ((const float4*)j.x)[idx];
        float4 pv = ((const float4*)j.pos)[idx];
        u16x4 hh;
        hh[0] = f2bf(xv.x + pv.x); hh[1] = f2bf(xv.y + pv.y);
        hh[2] = f2bf(xv.z + pv.z); hh[3] = f2bf(xv.w + pv.w);
        ((u16x4*)j.h)[idx] = hh;
        ((u16x4*)j.h)[idx + (T * D / 4)] = hh;
        return;
    }
    int m = blockIdx.z >> 2, slice = blockIdx.z & 3;
    int R = (m == 5) ? 1024 : 512;
    int C = (m == 4) ? 1024 : 512;
    if (blockIdx.x * 32 >= C || blockIdx.y * 32 >= R) return;
    const float* in = j.src[m] + (size_t)slice * R * C;
    u16* out = j.dst[m] + (size_t)slice * R * C;
    int tx = tid & 31, ty = tid >> 5;
    int x = blockIdx.x * 32 + tx;
    int y0 = blockIdx.y * 32;
#pragma unroll
    for (int i = 0; i < 4; i++)
        tile[ty + i * 8][tx] = in[(size_t)(y0 + ty + i * 8) * C + x];
    __syncthreads();
    int ox = y0 + tx;
#pragma unroll
    for (int i = 0; i < 4; i++)
        out[(size_t)(blockIdx.x * 32 + ty + i * 8) * R + ox] = f2bf(tile[tx][ty + i * 8]);
}

// ---------------- LayerNorm over bf16 h + optional bf16-partial fold -------
__global__ __launch_bounds__(256) void ln_res_kernel(u16* __restrict__ h,
                                                     const u16* __restrict__ part,
                                                     const float* __restrict__ wp,
                                                     const float* __restrict__ bp,
                                                     u16* __restrict__ out, int l) {
    int row = blockIdx.x * 4 + (threadIdx.x >> 6);
    int lane = threadIdx.x & 63;
    int s = row >> 11;
    int c0 = lane * 4;
    u16* xr = h + (size_t)row * D;
    u16x4 h0 = *(const u16x4*)(xr + c0);
    u16x4 h1 = *(const u16x4*)(xr + c0 + 256);
    float4 v0, v1;
    v0.x = bf2f(h0[0]); v0.y = bf2f(h0[1]); v0.z = bf2f(h0[2]); v0.w = bf2f(h0[3]);
    v1.x = bf2f(h1[0]); v1.y = bf2f(h1[1]); v1.z = bf2f(h1[2]); v1.w = bf2f(h1[3]);
    if (part) {
        const u16* p0r = part + (size_t)s * 2 * T * D + (size_t)(row & (T - 1)) * D;
        const u16* p1r = p0r + (size_t)T * D;
        u16x4 a0 = *(const u16x4*)(p0r + c0), a1 = *(const u16x4*)(p0r + c0 + 256);
        u16x4 e0 = *(const u16x4*)(p1r + c0), e1 = *(const u16x4*)(p1r + c0 + 256);
        v0.x += bf2f(a0[0]) + bf2f(e0[0]); v0.y += bf2f(a0[1]) + bf2f(e0[1]);
        v0.z += bf2f(a0[2]) + bf2f(e0[2]); v0.w += bf2f(a0[3]) + bf2f(e0[3]);
        v1.x += bf2f(a1[0]) + bf2f(e1[0]); v1.y += bf2f(a1[1]) + bf2f(e1[1]);
        v1.z += bf2f(a1[2]) + bf2f(e1[2]); v1.w += bf2f(a1[3]) + bf2f(e1[3]);
        u16x4 s0, s1;
        s0[0] = f2bf(v0.x); s0[1] = f2bf(v0.y); s0[2] = f2bf(v0.z); s0[3] = f2bf(v0.w);
        s1[0] = f2bf(v1.x); s1[1] = f2bf(v1.y); s1[2] = f2bf(v1.z); s1[3] = f2bf(v1.w);
        *(u16x4*)(xr + c0) = s0;
        *(u16x4*)(xr + c0 + 256) = s1;
    }
    float sum = v0.x + v0.y + v0.z + v0.w + v1.x + v1.y + v1.z + v1.w;
    float sq = v0.x*v0.x + v0.y*v0.y + v0.z*v0.z + v0.w*v0.w
             + v1.x*v1.x + v1.y*v1.y + v1.z*v1.z + v1.w*v1.w;
#pragma unroll
    for (int d2 = 1; d2 < 64; d2 <<= 1) { sum += __shfl_xor(sum, d2); sq += __shfl_xor(sq, d2); }
    float mu = sum * (1.0f / D);
    float var = sq * (1.0f / D) - mu * mu;
    float rstd = rsqrtf(var + 1e-5f);
    const float* w = wp + (size_t)(s * L + l) * D;
    const float* b = bp + (size_t)(s * L + l) * D;
    u16x4 p0, p1;
#pragma unroll
    for (int jj = 0; jj < 4; jj++) {
        float a = (jj == 0 ? v0.x : jj == 1 ? v0.y : jj == 2 ? v0.z : v0.w);
        p0[jj] = f2bf((a - mu) * rstd * w[c0 + jj] + b[c0 + jj]);
        float c = (jj == 0 ? v1.x : jj == 1 ? v1.y : jj == 2 ? v1.z : v1.w);
        p1[jj] = f2bf((c - mu) * rstd * w[c0 + 256 + jj] + b[c0 + 256 + jj]);
    }
    *(u16x4*)(out + (size_t)row * D + c0) = p0;
    *(u16x4*)(out + (size_t)row * D + c0 + 256) = p1;
}

// ---------------- Final LayerNorm (+ bf16 partial fold) -> fp32 out --------
__global__ __launch_bounds__(256) void lnf_kernel(const u16* __restrict__ h,
                                                  const u16* __restrict__ part,
                                                  const float* __restrict__ w,
                                                  const float* __restrict__ b,
                                                  float* __restrict__ out) {
    int row = blockIdx.x * 4 + (threadIdx.x >> 6);
    int lane = threadIdx.x & 63;
    int s = row >> 11;
    int c0 = lane * 4;
    const u16* xr = h + (size_t)row * D;
    u16x4 h0 = *(const u16x4*)(xr + c0);
    u16x4 h1 = *(const u16x4*)(xr + c0 + 256);
    float4 v0, v1;
    v0.x = bf2f(h0[0]); v0.y = bf2f(h0[1]); v0.z = bf2f(h0[2]); v0.w = bf2f(h0[3]);
    v1.x = bf2f(h1[0]); v1.y = bf2f(h1[1]); v1.z = bf2f(h1[2]); v1.w = bf2f(h1[3]);
    const u16* p0r = part + (size_t)s * 2 * T * D + (size_t)(row & (T - 1)) * D;
    const u16* p1r = p0r + (size_t)T * D;
    u16x4 a0 = *(const u16x4*)(p0r + c0), a1 = *(const u16x4*)(p0r + c0 + 256);
    u16x4 e0 = *(const u16x4*)(p1r + c0), e1 = *(const u16x4*)(p1r + c0 + 256);
    v0.x += bf2f(a0[0]) + bf2f(e0[0]); v0.y += bf2f(a0[1]) + bf2f(e0[1]);
    v0.z += bf2f(a0[2]) + bf2f(e0[2]); v0.w += bf2f(a0[3]) + bf2f(e0[3]);
    v1.x += bf2f(a1[0]) + bf2f(e1[0]); v1.y += bf2f(a1[1]) + bf2f(e1[1]);
    v1.z += bf2f(a1[2]) + bf2f(e1[2]); v1.w += bf2f(a1[3]) + bf2f(e1[3]);
    float sum = v0.x + v0.y + v0.z + v0.w + v1.x + v1.y + v1.z + v1.w;
    float sq = v0.x*v0.x + v0.y*v0.y + v0.z*v0.z + v0.w*v0.w
             + v1.x*v1.x + v1.y*v1.y + v1.z*v1.z + v1.w*v1.w;
#pragma unroll
    for (int d2 = 1; d2 < 64; d2 <<= 1) { sum += __shfl_xor(sum, d2); sq += __shfl_xor(sq, d2); }
    float mu = sum * (1.0f / D);
    float var = sq * (1.0f / D) - mu * mu;
    float rstd = rsqrtf(var + 1e-5f);
    float4 r0, r1;
    r0.x = (v0.x - mu) * rstd * w[c0+0] + b[c0+0];
    r0.y = (v0.y - mu) * rstd * w[c0+1] + b[c0+1];
    r0.z = (v0.z - mu) * rstd * w[c0+2] + b[c0+2];
    r0.w = (v0.w - mu) * rstd * w[c0+3] + b[c0+3];
    r1.x = (v1.x - mu) * rstd * w[c0+256+0] + b[c0+256+0];
    r1.y = (v1.y - mu) * rstd * w[c0+256+1] + b[c0+256+1];
    r1.z = (v1.z - mu) * rstd * w[c0+256+2] + b[c0+256+2];
    r1.w = (v1.w - mu) * rstd * w[c0+256+3] + b[c0+256+3];
    *(float4*)(out + (size_t)row * D + c0) = r0;
    *(float4*)(out + (size_t)row * D + c0 + 256) = r1;
}

// ---------------- 64x64-tile bf16 GEMM, BK=64 (LDS, global_load_lds) -------
struct GemmPtrs {
    const u16* A[6];
    const u16* Bt[6];
    const float* bias[6];
    void* C[6];
};

#define EPI_QKV  0   // bf16 store; pidx%3==2 -> store transposed into [D][T]
#define EPI_GELU 1   // bf16 store with exact gelu
#define EPI_PART 2   // bf16 store to partial buffer C + kc*M*N

template <int EPI>
__global__ __launch_bounds__(256) void gemm_kernel(GemmPtrs p, int M, int N, int K, int KS) {
    __shared__ __align__(16) u16 lA[2][64 * 32];
    __shared__ __align__(16) u16 lB[2][64 * 32];
    int nchunk = K / KS;
    int pidx = blockIdx.z / nchunk;
    int kc = blockIdx.z % nchunk;
    int koff = kc * KS;
    const u16* A = p.A[pidx];
    const u16* Bt = p.Bt[pidx];
    int m0 = blockIdx.y * 64, n0 = blockIdx.x * 64;
    int tid = threadIdx.x;
    int lane = tid & 63, wave = tid >> 6;
    int wx = wave & 1, wy = wave >> 1;
    int l16 = lane & 15, q4 = lane >> 4;
    const u16* ag = A + (size_t)(m0 + (tid >> 2)) * K + koff + (tid & 3) * 8;
    const u16* bg = Bt + (size_t)(n0 + (tid >> 2)) * K + koff + (tid & 3) * 8;
    floatx4 acc[2][2] = {};
    for (int k0 = 0; k0 < KS; k0 += 64) {
        __syncthreads();
#pragma unroll
        for (int kh = 0; kh < 2; kh++) {
            load_lds16(ag + k0 + kh * 32, &lA[kh][tid * 8]);
            load_lds16(bg + k0 + kh * 32, &lB[kh][tid * 8]);
        }
        __syncthreads();
#pragma unroll
        for (int kh = 0; kh < 2; kh++) {
            shortx8 af[2], bf[2];
#pragma unroll
            for (int t = 0; t < 2; t++) {
                af[t] = *(const shortx8*)(&lA[kh][(wy * 32 + t * 16 + l16) * 32 + q4 * 8]);
                bf[t] = *(const shortx8*)(&lB[kh][(wx * 32 + t * 16 + l16) * 32 + q4 * 8]);
            }
#pragma unroll
            for (int i = 0; i < 2; i++)
#pragma unroll
                for (int j = 0; j < 2; j++)
                    acc[i][j] = __builtin_amdgcn_mfma_f32_16x16x32_bf16(af[i], bf[j], acc[i][j], 0, 0, 0);
        }
    }
    const float* bias = p.bias[pidx];
    bool vtrans = (EPI == EPI_QKV) && (pidx % 3 == 2);
#pragma unroll
    for (int i = 0; i < 2; i++) {
        int row0 = m0 + wy * 32 + i * 16 + q4 * 4;
#pragma unroll
        for (int j = 0; j < 2; j++) {
            int col = n0 + wx * 32 + j * 16 + l16;
            float bz = (kc == 0) ? bias[col] : 0.0f;
            floatx4 a = acc[i][j];
            if (EPI == EPI_QKV) {
                if (vtrans) {
                    u16x4 pk;
#pragma unroll
                    for (int r = 0; r < 4; r++) pk[r] = f2bf(a[r] + bz);
                    *(u16x4*)((u16*)p.C[pidx] + (size_t)col * M + row0) = pk;
                } else {
#pragma unroll
                    for (int r = 0; r < 4; r++)
                        ((u16*)p.C[pidx])[(size_t)(row0 + r) * N + col] = f2bf(a[r] + bz);
                }
            } else if (EPI == EPI_GELU) {
#pragma unroll
                for (int r = 0; r < 4; r++) {
                    float v = a[r] + bz;
                    float g = 0.5f * v * (1.0f + erff(v * 0.70710678118f));
                    ((u16*)p.C[pidx])[(size_t)(row0 + r) * N + col] = f2bf(g);
                }
            } else {
#pragma unroll
                for (int r = 0; r < 4; r++)
                    ((u16*)p.C[pidx])[(size_t)kc * M * N + (size_t)(row0 + r) * N + col] = f2bf(a[r] + bz);
            }
        }
    }
}

// ---------------- banded flash attention, software-pipelined K/V loads -----
__global__ __launch_bounds__(256) void attn_kernel(const u16* __restrict__ qg,
                                                   const u16* __restrict__ kg,
                                                   const u16* __restrict__ vtg,
                                                   u16* __restrict__ ao,
                                                   int bw0, int bw1) {
    __shared__ __align__(16) u16 pbuf[4][16 * 32];
    __shared__ float cl[4][16];
    __shared__ float co[4][16][64];
    int s = blockIdx.z, hh = blockIdx.y, q0 = blockIdx.x * 16;
    int bw = (s == 0) ? bw0 : bw1;
    int tid = threadIdx.x, wave = tid >> 6, lane = tid & 63;
    int l16 = lane & 15, q4 = lane >> 4;
    const u16* Q = qg + (size_t)s * T * D;
    const u16* Kp = kg + (size_t)s * T * D;
    const u16* V = vtg + (size_t)s * D * T;
    int hd = hh * DH;
    shortx8 qf0 = *(const shortx8*)(Q + (size_t)(q0 + l16) * D + hd + q4 * 8);
    shortx8 qf1 = *(const shortx8*)(Q + (size_t)(q0 + l16) * D + hd + 32 + q4 * 8);
    floatx4 o[4] = {};
    float lsum[4] = {};
    int klo = q0 - bw; if (klo < 0) klo = 0; klo &= ~31;
    int khi = q0 + 15;
    u16* pw = pbuf[wave];
    int kt0 = klo + wave * 32;
    shortx8 kf0, kf1, kf2, kf3, vf0, vf1, vf2, vf3;
    if (kt0 <= khi) {
        kf0 = *(const shortx8*)(Kp + (size_t)(kt0 + l16) * D + hd + q4 * 8);
        kf1 = *(const shortx8*)(Kp + (size_t)(kt0 + l16) * D + hd + 32 + q4 * 8);
        kf2 = *(const shortx8*)(Kp + (size_t)(kt0 + 16 + l16) * D + hd + q4 * 8);
        kf3 = *(const shortx8*)(Kp + (size_t)(kt0 + 16 + l16) * D + hd + 32 + q4 * 8);
        vf0 = *(const shortx8*)(V + (size_t)(hd + 0 * 16 + l16) * T + kt0 + q4 * 8);
        vf1 = *(const shortx8*)(V + (size_t)(hd + 1 * 16 + l16) * T + kt0 + q4 * 8);
        vf2 = *(const shortx8*)(V + (size_t)(hd + 2 * 16 + l16) * T + kt0 + q4 * 8);
        vf3 = *(const shortx8*)(V + (size_t)(hd + 3 * 16 + l16) * T + kt0 + q4 * 8);
    }
    for (int kt = kt0; kt <= khi; kt += 128) {
        floatx4 s0 = {}, s1 = {};
        s0 = __builtin_amdgcn_mfma_f32_16x16x32_bf16(qf0, kf0, s0, 0, 0, 0);
        s0 = __builtin_amdgcn_mfma_f32_16x16x32_bf16(qf1, kf1, s0, 0, 0, 0);
        s1 = __builtin_amdgcn_mfma_f32_16x16x32_bf16(qf0, kf2, s1, 0, 0, 0);
        s1 = __builtin_amdgcn_mfma_f32_16x16x32_bf16(qf1, kf3, s1, 0, 0, 0);
        int ktn = kt + 128;
        shortx8 nk0, nk1, nk2, nk3, nv0, nv1, nv2, nv3;
        if (ktn <= khi) {
            nk0 = *(const shortx8*)(Kp + (size_t)(ktn + l16) * D + hd + q4 * 8);
            nk1 = *(const shortx8*)(Kp + (size_t)(ktn + l16) * D + hd + 32 + q4 * 8);
            nk2 = *(const shortx8*)(Kp + (size_t)(ktn + 16 + l16) * D + hd + q4 * 8);
            nk3 = *(const shortx8*)(Kp + (size_t)(ktn + 16 + l16) * D + hd + 32 + q4 * 8);
            nv0 = *(const shortx8*)(V + (size_t)(hd + 0 * 16 + l16) * T + ktn + q4 * 8);
            nv1 = *(const shortx8*)(V + (size_t)(hd + 1 * 16 + l16) * T + ktn + q4 * 8);
            nv2 = *(const shortx8*)(V + (size_t)(hd + 2 * 16 + l16) * T + ktn + q4 * 8);
            nv3 = *(const shortx8*)(V + (size_t)(hd + 3 * 16 + l16) * T + ktn + q4 * 8);
        }
#pragma unroll
        for (int r = 0; r < 4; r++) {
            int row = q0 + q4 * 4 + r;
            int c0 = kt + l16, c1 = kt + 16 + l16;
            float p0 = (c0 <= row && c0 >= row - bw) ? __expf(s0[r] * 0.125f) : 0.0f;
            float p1 = (c1 <= row && c1 >= row - bw) ? __expf(s1[r] * 0.125f) : 0.0f;
            lsum[r] += p0 + p1;
            pw[(q4 * 4 + r) * 32 + l16] = f2bf(p0);
            pw[(q4 * 4 + r) * 32 + 16 + l16] = f2bf(p1);
        }
        shortx8 pf = *(const shortx8*)(pw + l16 * 32 + q4 * 8);
        o[0] = __builtin_amdgcn_mfma_f32_16x16x32_bf16(pf, vf0, o[0], 0, 0, 0);
        o[1] = __builtin_amdgcn_mfma_f32_16x16x32_bf16(pf, vf1, o[1], 0, 0, 0);
        o[2] = __builtin_amdgcn_mfma_f32_16x16x32_bf16(pf, vf2, o[2], 0, 0, 0);
        o[3] = __builtin_amdgcn_mfma_f32_16x16x32_bf16(pf, vf3, o[3], 0, 0, 0);
        kf0 = nk0; kf1 = nk1; kf2 = nk2; kf3 = nk3;
        vf0 = nv0; vf1 = nv1; vf2 = nv2; vf3 = nv3;
    }
#pragma unroll
    for (int r = 0; r < 4; r++) {
#pragma unroll
        for (int d2 = 1; d2 < 16; d2 <<= 1) lsum[r] += __shfl_xor(lsum[r], d2);
    }
    if (l16 == 0) {
#pragma unroll
        for (int r = 0; r < 4; r++) cl[wave][q4 * 4 + r] = lsum[r];
    }
#pragma unroll
    for (int n = 0; n < 4; n++)
#pragma unroll
        for (int r = 0; r < 4; r++)
            co[wave][q4 * 4 + r][n * 16 + l16] = o[n][r];
    __syncthreads();
#pragma unroll
    for (int i = 0; i < 4; i++) {
        int idx = tid + i * 256;
        int row = idx >> 6, col = idx & 63;
        float Ls = cl[0][row] + cl[1][row] + cl[2][row] + cl[3][row];
        float O = co[0][row][col] + co[1][row][col] + co[2][row][col] + co[3][row][col];
        ao[(size_t)s * T * D + (size_t)(q0 + row) * D + hd + col] = f2bf(O / Ls);
    }
}

// ---------------------------------------------------------------------------
extern "C" void kernel_launch(void* const* d_in, const int* in_sizes, int n_in,
                              void* d_out, int out_size, void* d_ws, size_t ws_size,
                              hipStream_t stream) {
    (void)in_sizes; (void)n_in; (void)out_size; (void)ws_size;
    const float* x     = (const float*)d_in[0];
    const float* pos   = (const float*)d_in[1];
    const float* ln1_w = (const float*)d_in[2];
    const float* ln1_b = (const float*)d_in[3];
    const float* ln2_w = (const float*)d_in[4];
    const float* ln2_b = (const float*)d_in[5];
    const float* Wq    = (const float*)d_in[6];
    const float* bq    = (const float*)d_in[7];
    const float* Wk    = (const float*)d_in[8];
    const float* bk    = (const float*)d_in[9];
    const float* Wv    = (const float*)d_in[10];
    const float* bv    = (const float*)d_in[11];
    const float* Wo    = (const float*)d_in[12];
    const float* bo    = (const float*)d_in[13];
    const float* W1    = (const float*)d_in[14];
    const float* b1    = (const float*)d_in[15];
    const float* W2    = (const float*)d_in[16];
    const float* b2    = (const float*)d_in[17];
    const float* lnf_w = (const float*)d_in[18];
    const float* lnf_b = (const float*)d_in[19];

    char* ws = (char*)d_ws;
    size_t off = 0;
    auto alloc = [&](size_t bytes) { void* p = ws + off; off += (bytes + 255) & ~(size_t)255; return p; };
    u16* WqT = (u16*)alloc((size_t)4 * 512 * 512 * 2);
    u16* WkT = (u16*)alloc((size_t)4 * 512 * 512 * 2);
    u16* WvT = (u16*)alloc((size_t)4 * 512 * 512 * 2);
    u16* WoT = (u16*)alloc((size_t)4 * 512 * 512 * 2);
    u16* W1T = (u16*)alloc((size_t)4 * 512 * 1024 * 2);
    u16* W2T = (u16*)alloc((size_t)4 * 1024 * 512 * 2);
    u16* h   = (u16*)alloc((size_t)2 * T * D * 2);
    u16* xln = (u16*)alloc((size_t)2 * T * D * 2);
    u16* qb  = (u16*)alloc((size_t)2 * T * D * 2);
    u16* kb  = (u16*)alloc((size_t)2 * T * D * 2);
    u16* vt  = (u16*)alloc((size_t)2 * T * D * 2);
    u16* ao  = (u16*)alloc((size_t)2 * T * D * 2);
    u16* ff  = (u16*)alloc((size_t)2 * T * 1024 * 2);
    u16* pp = (u16*)alloc((size_t)2 * 2 * T * D * 2);  // proj partials bf16 [s][2][T][D]
    u16* pf = (u16*)alloc((size_t)2 * 2 * T * D * 2);  // ff2 partials bf16

    TransJobs tj;
    tj.src[0] = Wq; tj.dst[0] = WqT;
    tj.src[1] = Wk; tj.dst[1] = WkT;
    tj.src[2] = Wv; tj.dst[2] = WvT;
    tj.src[3] = Wo; tj.dst[3] = WoT;
    tj.src[4] = W1; tj.dst[4] = W1T;
    tj.src[5] = W2; tj.dst[5] = W2T;
    tj.x = x; tj.pos = pos; tj.h = h;
    pre_kernel<<<dim3(32, 32, 25), 256, 0, stream>>>(tj);

    for (int l = 0; l < L; l++) {
        ln_res_kernel<<<(2 * T) / 4, 256, 0, stream>>>(h, l == 0 ? nullptr : pf,
                                                       ln1_w, ln1_b, xln, l);

        GemmPtrs g{};
        for (int s = 0; s < 2; s++) {
            int wo = s * L + l;
            const u16* a = xln + (size_t)s * T * D;
            g.A[s * 3 + 0] = a; g.Bt[s * 3 + 0] = WqT + (size_t)wo * 512 * 512;
            g.bias[s * 3 + 0] = bq + (size_t)wo * 512; g.C[s * 3 + 0] = qb + (size_t)s * T * D;
            g.A[s * 3 + 1] = a; g.Bt[s * 3 + 1] = WkT + (size_t)wo * 512 * 512;
            g.bias[s * 3 + 1] = bk + (size_t)wo * 512; g.C[s * 3 + 1] = kb + (size_t)s * T * D;
            g.A[s * 3 + 2] = a; g.Bt[s * 3 + 2] = WvT + (size_t)wo * 512 * 512;
            g.bias[s * 3 + 2] = bv + (size_t)wo * 512; g.C[s * 3 + 2] = vt + (size_t)s * T * D;
        }
        gemm_kernel<EPI_QKV><<<dim3(8, 32, 6), 256, 0, stream>>>(g, T, 512, 512, 512);

        attn_kernel<<<dim3(128, 8, 2), 256, 0, stream>>>(qb, kb, vt, ao, 999, 9);

        GemmPtrs gp{};
        for (int s = 0; s < 2; s++) {
            int wo = s * L + l;
            gp.A[s] = ao + (size_t)s * T * D;
            gp.Bt[s] = WoT + (size_t)wo * 512 * 512;
            gp.bias[s] = bo + (size_t)wo * 512;
            gp.C[s] = pp + (size_t)s * 2 * T * D;
        }
        gemm_kernel<EPI_PART><<<dim3(8, 32, 4), 256, 0, stream>>>(gp, T, 512, 512, 256);

        ln_res_kernel<<<(2 * T) / 4, 256, 0, stream>>>(h, pp, ln2_w, ln2_b, xln, l);

        GemmPtrs g1{};
        for (int s = 0; s < 2; s++) {
            int wo = s * L + l;
            g1.A[s] = xln + (size_t)s * T * D;
            g1.Bt[s] = W1T + (size_t)wo * 512 * 1024;
            g1.bias[s] = b1 + (size_t)wo * 1024;
            g1.C[s] = ff + (size_t)s * T * 1024;
        }
        gemm_kernel<EPI_GELU><<<dim3(16, 32, 2), 256, 0, stream>>>(g1, T, 1024, 512, 512);

        GemmPtrs g2{};
        for (int s = 0; s < 2; s++) {
            int wo = s * L + l;
            g2.A[s] = ff + (size_t)s * T * 1024;
            g2.Bt[s] = W2T + (size_t)wo * 1024 * 512;
            g2.bias[s] = b2 + (size_t)wo * 512;
            g2.C[s] = pf + (size_t)s * 2 * T * D;
        }
        gemm_kernel<EPI_PART><<<dim3(8, 32, 4), 256, 0, stream>>>(g2, T, 512, 1024, 512);
    }

    lnf_kernel<<<(2 * T) / 4, 256, 0, stream>>>(h, pf, lnf_w, lnf_b, (float*)d_out);
}